// Round 1
// baseline (519.364 us; speedup 1.0000x reference)
//
#include <hip/hip_runtime.h>
#include <math.h>

typedef unsigned short u16;
typedef unsigned int   u32;

using f32x4 = __attribute__((ext_vector_type(4))) float;
using s16x8 = __attribute__((ext_vector_type(8))) short;

// ---------- helpers ----------
__device__ __forceinline__ u16 f2b(float f) {           // fp32 -> bf16 RNE
    u32 u = __float_as_uint(f);
    u += 0x7FFFu + ((u >> 16) & 1u);
    return (u16)(u >> 16);
}
__device__ __forceinline__ float b2f(u16 u) { return __uint_as_float(((u32)u) << 16); }

// window-order row R -> natural token row (b*256 + i*16 + j)
__device__ __forceinline__ int natrow(int R) {
    int b = R >> 8, r8 = R & 255, w = r8 >> 2, t = r8 & 3;
    return (b << 8) + ((((w >> 3) << 1) + (t >> 1)) << 4) + ((w & 7) << 1) + (t & 1);
}

__device__ __forceinline__ void gll16(const void* g, void* l) {
    __builtin_amdgcn_global_load_lds(
        (const __attribute__((address_space(1))) void*)g,
        (__attribute__((address_space(3))) void*)l, 16, 0, 0);
}

// ---------- weight repack: [R][C] f32 -> [C][R] bf16 (batched over z) ----------
__global__ __launch_bounds__(256) void transpose_w(
    const float* __restrict__ in, u16* __restrict__ out, int R, int C)
{
    __shared__ float tile[32][33];
    const int z = blockIdx.z;
    in  += (size_t)z * R * C;
    out += (size_t)z * R * C;
    const int tx = threadIdx.x, ty = threadIdx.y;
    const int c  = blockIdx.x * 32 + tx;
    const int r0 = blockIdx.y * 32;
#pragma unroll
    for (int i = 0; i < 32; i += 8) tile[ty + i][tx] = in[(size_t)(r0 + ty + i) * C + c];
    __syncthreads();
    const int orow0 = blockIdx.x * 32;
    const int ocol  = r0 + tx;
#pragma unroll
    for (int i = 0; i < 32; i += 8)
        out[(size_t)(orow0 + ty + i) * R + ocol] = f2b(tile[tx][ty + i]);
}

// ---------- LayerNorm (optionally with window-partition gather) ----------
// one block (256 thr) per output row; 1024 elements per row
template<int MAP, int WF32>
__global__ __launch_bounds__(256) void ln_kernel(
    const float* __restrict__ X, const float* __restrict__ g, const float* __restrict__ bta,
    float* __restrict__ outF, u16* __restrict__ outB)
{
    const int R   = blockIdx.x;
    const int src = MAP ? natrow(R) : R;
    const float4 v = ((const float4*)(X + (size_t)src * 1024))[threadIdx.x];
    float s  = v.x + v.y + v.z + v.w;
    float s2 = v.x * v.x + v.y * v.y + v.z * v.z + v.w * v.w;
#pragma unroll
    for (int o = 32; o; o >>= 1) { s += __shfl_xor(s, o); s2 += __shfl_xor(s2, o); }
    __shared__ float red[8];
    const int w = threadIdx.x >> 6, l = threadIdx.x & 63;
    if (l == 0) { red[w] = s; red[w + 4] = s2; }
    __syncthreads();
    s  = red[0] + red[1] + red[2] + red[3];
    s2 = red[4] + red[5] + red[6] + red[7];
    const float mean = s * (1.f / 1024.f);
    const float var  = s2 * (1.f / 1024.f) - mean * mean;
    const float rinv = rsqrtf(var + 1e-5f);
    const float4 gv = ((const float4*)g)[threadIdx.x];
    const float4 bv = ((const float4*)bta)[threadIdx.x];
    const float y0 = (v.x - mean) * rinv * gv.x + bv.x;
    const float y1 = (v.y - mean) * rinv * gv.y + bv.y;
    const float y2 = (v.z - mean) * rinv * gv.z + bv.z;
    const float y3 = (v.w - mean) * rinv * gv.w + bv.w;
    if (WF32) ((float4*)(outF + (size_t)R * 1024))[threadIdx.x] = make_float4(y0, y1, y2, y3);
    ((ushort4*)(outB + (size_t)R * 1024))[threadIdx.x] =
        make_ushort4(f2b(y0), f2b(y1), f2b(y2), f2b(y3));
}

// ---------- GEMM: C[M][N] = A[M][K](bf16) @ Bt[N][K](bf16)^T, m97 structure ----------
// MODE 0: store bf16
// MODE 1: +bias +resid -> f32 (in-place capable: Out==resid)
// MODE 2: gelu(+bias) -> bf16
// MODE 3: +bias +resid -> f32 at permuted (natural) row
template<int MODE>
__global__ __launch_bounds__(256) void gemm_bt(
    const u16* __restrict__ A, const u16* __restrict__ Bt,
    const float* __restrict__ bias, const float* resid,
    void* Out, int M, int N, int K)
{
    __shared__ u16 As[128 * 64];
    __shared__ u16 Bs[128 * 64];
    const int tid = threadIdx.x;
    const int w = tid >> 6, l = tid & 63;
    const int wr = w >> 1, wc = w & 1;
    const int lr = l & 15, kg = l >> 4;
    const int row0 = blockIdx.x * 128, col0 = blockIdx.y * 128;
    f32x4 acc[4][4] = {};
    for (int kt = 0; kt < K; kt += 64) {
#pragma unroll
        for (int i = 0; i < 4; ++i) {
            const int q = i * 2048 + tid * 8;
            const int r = q >> 6, c = q & 63;
            gll16(A  + (size_t)(row0 + r) * K + kt + c, (char*)As + i * 4096 + w * 1024);
            gll16(Bt + (size_t)(col0 + r) * K + kt + c, (char*)Bs + i * 4096 + w * 1024);
        }
        __syncthreads();
#pragma unroll
        for (int kk = 0; kk < 2; ++kk) {
            s16x8 a[4], b[4];
#pragma unroll
            for (int m = 0; m < 4; ++m)
                a[m] = *(const s16x8*)&As[(wr * 64 + m * 16 + lr) * 64 + kk * 32 + kg * 8];
#pragma unroll
            for (int n = 0; n < 4; ++n)
                b[n] = *(const s16x8*)&Bs[(wc * 64 + n * 16 + lr) * 64 + kk * 32 + kg * 8];
#pragma unroll
            for (int m = 0; m < 4; ++m)
#pragma unroll
                for (int n = 0; n < 4; ++n)
                    acc[m][n] = __builtin_amdgcn_mfma_f32_16x16x32_bf16(a[m], b[n], acc[m][n], 0, 0, 0);
        }
        __syncthreads();
    }
#pragma unroll
    for (int m = 0; m < 4; ++m) {
        const int grb = row0 + wr * 64 + m * 16 + kg * 4;
#pragma unroll
        for (int n = 0; n < 4; ++n) {
            const int gc = col0 + wc * 64 + n * 16 + lr;
#pragma unroll
            for (int j = 0; j < 4; ++j) {
                const int gr = grb + j;
                const float v = acc[m][n][j];
                if (MODE == 0) {
                    ((u16*)Out)[(size_t)gr * N + gc] = f2b(v);
                } else if (MODE == 1) {
                    const float rs = v + bias[gc] + resid[(size_t)gr * N + gc];
                    ((float*)Out)[(size_t)gr * N + gc] = rs;
                } else if (MODE == 2) {
                    const float t = v + bias[gc];
                    const float ge = 0.5f * t * (1.f + erff(t * 0.70710678118f));
                    ((u16*)Out)[(size_t)gr * N + gc] = f2b(ge);
                } else {
                    const float rs = v + bias[gc] + resid[(size_t)gr * N + gc];
                    ((float*)Out)[(size_t)natrow(gr) * N + gc] = rs;
                }
            }
        }
    }
}

// ---------- tiny windowed attention: one wave per (window n, head h) ----------
__global__ __launch_bounds__(256) void attn_kernel(
    const u16* __restrict__ Q, const u16* __restrict__ Kb,
    const u16* __restrict__ Vb, u16* __restrict__ O)
{
    const int tid = threadIdx.x;
    const int w = tid >> 6, l = tid & 63;
    const int p = blockIdx.x * 4 + w;     // 65536 (n,h) pairs
    const int n = p >> 4, h = p & 15;
    const size_t base = (size_t)n * 4096 + h * 64 + l;
    float q[4], k[4], v[4];
#pragma unroll
    for (int t = 0; t < 4; ++t) {
        q[t] = b2f(Q[base + t * 1024]);
        k[t] = b2f(Kb[base + t * 1024]);
        v[t] = b2f(Vb[base + t * 1024]);
    }
    const float scale = 0.03125f;         // C^-0.5 = 1/32 (d_model!)
#pragma unroll
    for (int t = 0; t < 4; ++t) {
        float s0 = q[t] * k[0], s1 = q[t] * k[1], s2 = q[t] * k[2], s3 = q[t] * k[3];
#pragma unroll
        for (int o = 32; o; o >>= 1) {
            s0 += __shfl_xor(s0, o); s1 += __shfl_xor(s1, o);
            s2 += __shfl_xor(s2, o); s3 += __shfl_xor(s3, o);
        }
        s0 *= scale; s1 *= scale; s2 *= scale; s3 *= scale;
        const float m = fmaxf(fmaxf(s0, s1), fmaxf(s2, s3));
        const float e0 = expf(s0 - m), e1 = expf(s1 - m), e2 = expf(s2 - m), e3 = expf(s3 - m);
        const float inv = 1.f / (e0 + e1 + e2 + e3);
        const float o_ = (e0 * v[0] + e1 * v[1] + e2 * v[2] + e3 * v[3]) * inv;
        O[base + t * 1024] = f2b(o_);
    }
}

// ---------- launch ----------
extern "C" void kernel_launch(void* const* d_in, const int* in_sizes, int n_in,
                              void* d_out, int out_size, void* d_ws, size_t ws_size,
                              hipStream_t stream)
{
    const float* x    = (const float*)d_in[0];
    const float* ln1g = (const float*)d_in[1];
    const float* ln1b = (const float*)d_in[2];
    const float* Wq   = (const float*)d_in[3];
    const float* Wk   = (const float*)d_in[4];
    const float* Wv   = (const float*)d_in[5];
    const float* Wp   = (const float*)d_in[6];
    const float* bp   = (const float*)d_in[7];
    const float* ln2g = (const float*)d_in[8];
    const float* ln2b = (const float*)d_in[9];
    const float* W1   = (const float*)d_in[10];
    const float* b1   = (const float*)d_in[11];
    const float* W2   = (const float*)d_in[12];
    const float* b2   = (const float*)d_in[13];
    float* out = (float*)d_out;

    char* ws = (char*)d_ws;
    const size_t MB = 1024 * 1024;
    float* xw_f = (float*)ws;                       // 64MB: xw fp32, becomes xr in-place
    u16*   xw_b = (u16*)(ws + 64 * MB);             // 32MB: xw bf16, later att_b
    u16*   qb   = (u16*)(ws + 96 * MB);             // 32MB: q, later ln2_b
    u16*   kb   = (u16*)(ws + 128 * MB);            // 32MB: k, later h1_b
    u16*   vb   = (u16*)(ws + 160 * MB);            // 32MB: v
    u16*   WqT  = (u16*)(ws + 192 * MB);            // 6 x 2MB bf16 [N][K] weights
    u16*   WkT  = WqT + (1u << 20);
    u16*   WvT  = WkT + (1u << 20);
    u16*   WpT  = WvT + (1u << 20);
    u16*   W1T  = WpT + (1u << 20);
    u16*   W2T  = W1T + (1u << 20);

    const int M = 16384, N = 1024, K = 1024;
    dim3 tpb(32, 8);
    // per-head [1024][64] -> [64][1024] blocks; concatenated heads give [N][K]
    transpose_w<<<dim3(2, 32, 16), tpb, 0, stream>>>(Wq, WqT, 1024, 64);
    transpose_w<<<dim3(2, 32, 16), tpb, 0, stream>>>(Wk, WkT, 1024, 64);
    transpose_w<<<dim3(2, 32, 16), tpb, 0, stream>>>(Wv, WvT, 1024, 64);
    transpose_w<<<dim3(32, 32, 1), tpb, 0, stream>>>(Wp, WpT, 1024, 1024);
    transpose_w<<<dim3(32, 32, 1), tpb, 0, stream>>>(W1, W1T, 1024, 1024);
    transpose_w<<<dim3(32, 32, 1), tpb, 0, stream>>>(W2, W2T, 1024, 1024);

    ln_kernel<1, 1><<<16384, 256, 0, stream>>>(x, ln1g, ln1b, xw_f, xw_b);

    dim3 gg(M / 128, N / 128);
    gemm_bt<0><<<gg, 256, 0, stream>>>(xw_b, WqT, nullptr, nullptr, qb, M, N, K);
    gemm_bt<0><<<gg, 256, 0, stream>>>(xw_b, WkT, nullptr, nullptr, kb, M, N, K);
    gemm_bt<0><<<gg, 256, 0, stream>>>(xw_b, WvT, nullptr, nullptr, vb, M, N, K);

    attn_kernel<<<16384, 256, 0, stream>>>(qb, kb, vb, xw_b);      // att -> xw_b slot

    // xr = att @ Wp + bp + xw   (in-place into xw_f)
    gemm_bt<1><<<gg, 256, 0, stream>>>(xw_b, WpT, bp, xw_f, xw_f, M, N, K);

    ln_kernel<0, 0><<<16384, 256, 0, stream>>>(xw_f, ln2g, ln2b, nullptr, qb);

    // h1 = gelu(ln2 @ W1 + b1)
    gemm_bt<2><<<gg, 256, 0, stream>>>(qb, W1T, b1, nullptr, kb, M, N, K);

    // out[natrow] = h1 @ W2 + b2 + xr
    gemm_bt<3><<<gg, 256, 0, stream>>>(kb, W2T, b2, xw_f, out, M, N, K);
}

// Round 2
// 453.948 us; speedup vs baseline: 1.1441x; 1.1441x over previous
//
#include <hip/hip_runtime.h>
#include <math.h>

typedef unsigned short u16;
typedef unsigned int   u32;

using f32x4 = __attribute__((ext_vector_type(4))) float;
using s16x8 = __attribute__((ext_vector_type(8))) short;

// ---------- helpers ----------
__device__ __forceinline__ u16 f2b(float f) {           // fp32 -> bf16 RNE
    u32 u = __float_as_uint(f);
    u += 0x7FFFu + ((u >> 16) & 1u);
    return (u16)(u >> 16);
}
__device__ __forceinline__ float b2f(u16 u) { return __uint_as_float(((u32)u) << 16); }

// window-order row R -> natural token row (b*256 + i*16 + j)
__device__ __forceinline__ int natrow(int R) {
    int b = R >> 8, r8 = R & 255, w = r8 >> 2, t = r8 & 3;
    return (b << 8) + ((((w >> 3) << 1) + (t >> 1)) << 4) + ((w & 7) << 1) + (t & 1);
}

__device__ __forceinline__ void gll16(const void* g, void* l) {
    __builtin_amdgcn_global_load_lds(
        (const __attribute__((address_space(1))) void*)g,
        (__attribute__((address_space(3))) void*)l, 16, 0, 0);
}

// ---------- weight repack: [R][C] f32 -> [C][R] bf16 (batched over z) ----------
__global__ __launch_bounds__(256) void transpose_w(
    const float* __restrict__ in, u16* __restrict__ out, int R, int C)
{
    __shared__ float tile[32][33];
    const int z = blockIdx.z;
    in  += (size_t)z * R * C;
    out += (size_t)z * R * C;
    const int tx = threadIdx.x, ty = threadIdx.y;
    const int c  = blockIdx.x * 32 + tx;
    const int r0 = blockIdx.y * 32;
#pragma unroll
    for (int i = 0; i < 32; i += 8) tile[ty + i][tx] = in[(size_t)(r0 + ty + i) * C + c];
    __syncthreads();
    const int orow0 = blockIdx.x * 32;
    const int ocol  = r0 + tx;
#pragma unroll
    for (int i = 0; i < 32; i += 8)
        out[(size_t)(orow0 + ty + i) * R + ocol] = f2b(tile[tx][ty + i]);
}

// ---------- LayerNorm (optionally with window-partition gather) ----------
template<int MAP, int WF32>
__global__ __launch_bounds__(256) void ln_kernel(
    const float* __restrict__ X, const float* __restrict__ g, const float* __restrict__ bta,
    float* __restrict__ outF, u16* __restrict__ outB)
{
    const int R   = blockIdx.x;
    const int src = MAP ? natrow(R) : R;
    const float4 v = ((const float4*)(X + (size_t)src * 1024))[threadIdx.x];
    float s  = v.x + v.y + v.z + v.w;
    float s2 = v.x * v.x + v.y * v.y + v.z * v.z + v.w * v.w;
#pragma unroll
    for (int o = 32; o; o >>= 1) { s += __shfl_xor(s, o); s2 += __shfl_xor(s2, o); }
    __shared__ float red[8];
    const int w = threadIdx.x >> 6, l = threadIdx.x & 63;
    if (l == 0) { red[w] = s; red[w + 4] = s2; }
    __syncthreads();
    s  = red[0] + red[1] + red[2] + red[3];
    s2 = red[4] + red[5] + red[6] + red[7];
    const float mean = s * (1.f / 1024.f);
    const float var  = s2 * (1.f / 1024.f) - mean * mean;
    const float rinv = rsqrtf(var + 1e-5f);
    const float4 gv = ((const float4*)g)[threadIdx.x];
    const float4 bv = ((const float4*)bta)[threadIdx.x];
    const float y0 = (v.x - mean) * rinv * gv.x + bv.x;
    const float y1 = (v.y - mean) * rinv * gv.y + bv.y;
    const float y2 = (v.z - mean) * rinv * gv.z + bv.z;
    const float y3 = (v.w - mean) * rinv * gv.w + bv.w;
    if (WF32) ((float4*)(outF + (size_t)R * 1024))[threadIdx.x] = make_float4(y0, y1, y2, y3);
    ((ushort4*)(outB + (size_t)R * 1024))[threadIdx.x] =
        make_ushort4(f2b(y0), f2b(y1), f2b(y2), f2b(y3));
}

// ---------- 256x256 8-wave GEMM, BK=64, swizzled LDS, counted-vmcnt pipeline ----------
// C[M][N] = A[M][K](bf16) @ Bt[N][K](bf16)^T
// MODE 0: store bf16   MODE 1: +bias+resid -> f32   MODE 2: gelu(+bias) -> bf16
// MODE 3: +bias+resid -> f32 at permuted (natural) row
//
// LDS (128KB dynamic): A: [d][half][128][64] bf16 at d*32K + half*16K (64KB)
//                      B: same at 64KB + ...
// Swizzle st_16x32: phys_byte = lin_byte ^ (((lin_byte>>9)&1)<<5)  (within half-tile)
// Stage order per tile t (issued during tile t-1 phases 0..3): A0,B0,A1,B1
// Quadrant per phase p: qm=p&1, qn=p>>1 -> phase p first-uses item staged >=3 phases ago.
// vmcnt(4) at end of every phase (2 loads/item/thread; newest 2 items may fly).
template<int MODE>
__global__ __launch_bounds__(512, 2) void gemm256(
    const u16* __restrict__ A, const u16* __restrict__ Bt,
    const float* __restrict__ bias, const float* __restrict__ resid,
    void* __restrict__ Out, int M, int N, int K, int NB)
{
    extern __shared__ char lds[];
    const int NT = K >> 6;
    const int nblk = gridDim.x;
    // XCD-chunked swizzle: consecutive logical blocks (same A panel) on same XCD
    const int lb = (blockIdx.x & 7) * (nblk >> 3) + (blockIdx.x >> 3);
    const int mb = lb / NB, nb = lb - mb * NB;
    const int row0 = mb * 256, col0 = nb * 256;
    const int tid = threadIdx.x;
    const int w = tid >> 6, l = tid & 63;
    const int wr = w >> 2, wc = w & 3;
    const int lr = l & 15, kg = l >> 4;
    const int xs = (lr & 4) << 3;                 // swizzle XOR for reads (bit5)
    const int koff[2] = { (kg * 16) ^ xs, (64 + kg * 16) ^ xs };
    const int abase_l = wr * 8192 + lr * 128;     // per-lane A row offset in half
    const int bbase_l = wc * 4096 + lr * 128;     // per-lane B row offset in half

    f32x4 acc[2][2][4][2] = {};                   // [qm][qn][i][n]

    auto stage = [&](int ts, int item) {          // item: 0=A0 1=B0 2=A1 3=B1
        if (ts >= NT) return;
        const int d = ts & 1;
        const int isB = item & 1, h = item >> 1;
        char* lbase = lds + (isB ? 65536 : 0) + d * 32768 + h * 16384;
        const u16* gptr = isB ? Bt : A;
        const int blk0 = (isB ? col0 : row0) + h * 128;
#pragma unroll
        for (int j = 0; j < 2; ++j) {
            const int p = j * 512 + tid;          // physical 16B chunk
            const int q = p ^ (((p >> 5) & 1) << 1);  // logical chunk (inverse swizzle)
            const int grow = blk0 + (q >> 3);
            const int gcol = ts * 64 + (q & 7) * 8;
            gll16(gptr + (size_t)grow * K + gcol, lbase + (j * 8 + w) * 1024);
        }
    };

    // prologue: tile 0 all items; A0,B0 must land (vmcnt(4)), A1,B1 may fly
    stage(0, 0); stage(0, 1); stage(0, 2); stage(0, 3);
    asm volatile("s_waitcnt vmcnt(4)" ::: "memory");
    __builtin_amdgcn_s_barrier();

    for (int t = 0; t < NT; ++t) {
        const int d = t & 1;
        const char* Ab = lds + d * 32768;
        const char* Bb = lds + 65536 + d * 32768;
#pragma unroll
        for (int p = 0; p < 4; ++p) {
            const int qm = p & 1, qn = p >> 1;
            s16x8 a[4][2], b[2][2];
#pragma unroll
            for (int kk = 0; kk < 2; ++kk) {
#pragma unroll
                for (int i = 0; i < 4; ++i)
                    a[i][kk] = *(const s16x8*)(Ab + qm * 16384 + abase_l + i * 2048 + koff[kk]);
#pragma unroll
                for (int n = 0; n < 2; ++n)
                    b[n][kk] = *(const s16x8*)(Bb + qn * 16384 + bbase_l + n * 2048 + koff[kk]);
            }
            stage(t + 1, p);                      // next tile, item p (other buffer)
            __builtin_amdgcn_sched_barrier(0);
            __builtin_amdgcn_s_barrier();
            asm volatile("s_waitcnt lgkmcnt(0)" ::: "memory");
            __builtin_amdgcn_sched_barrier(0);
            __builtin_amdgcn_s_setprio(1);
#pragma unroll
            for (int kk = 0; kk < 2; ++kk)
#pragma unroll
                for (int i = 0; i < 4; ++i)
#pragma unroll
                    for (int n = 0; n < 2; ++n)
                        acc[qm][qn][i][n] = __builtin_amdgcn_mfma_f32_16x16x32_bf16(
                            a[i][kk], b[n][kk], acc[qm][qn][i][n], 0, 0, 0);
            __builtin_amdgcn_s_setprio(0);
            __builtin_amdgcn_sched_barrier(0);
            if (t == NT - 1) {
                if (p == 0) { asm volatile("s_waitcnt vmcnt(0)" ::: "memory"); }
            } else {
                asm volatile("s_waitcnt vmcnt(4)" ::: "memory");
            }
            __builtin_amdgcn_s_barrier();
            __builtin_amdgcn_sched_barrier(0);
        }
    }

    // epilogue
#pragma unroll
    for (int qm = 0; qm < 2; ++qm)
#pragma unroll
    for (int i = 0; i < 4; ++i) {
        const int grb = row0 + qm * 128 + wr * 64 + i * 16 + kg * 4;
#pragma unroll
        for (int qn = 0; qn < 2; ++qn)
#pragma unroll
        for (int n = 0; n < 2; ++n) {
            const int gc = col0 + qn * 128 + wc * 32 + n * 16 + lr;
#pragma unroll
            for (int j = 0; j < 4; ++j) {
                const int gr = grb + j;
                const float v = acc[qm][qn][i][n][j];
                if (MODE == 0) {
                    ((u16*)Out)[(size_t)gr * N + gc] = f2b(v);
                } else if (MODE == 1) {
                    ((float*)Out)[(size_t)gr * N + gc] = v + bias[gc] + resid[(size_t)gr * N + gc];
                } else if (MODE == 2) {
                    const float tt = v + bias[gc];
                    ((u16*)Out)[(size_t)gr * N + gc] = f2b(0.5f * tt * (1.f + erff(tt * 0.70710678118f)));
                } else {
                    ((float*)Out)[(size_t)natrow(gr) * N + gc] = v + bias[gc] + resid[(size_t)gr * N + gc];
                }
            }
        }
    }
}

// ---------- tiny windowed attention on merged qkv [16384][3072] ----------
__global__ __launch_bounds__(256) void attn_kernel(
    const u16* __restrict__ QKV, u16* __restrict__ O)
{
    const int tid = threadIdx.x;
    const int w = tid >> 6, l = tid & 63;
    const int p = blockIdx.x * 4 + w;     // 65536 (n,h) pairs
    const int n = p >> 4, h = p & 15;
    const size_t rbase = (size_t)n * 4 * 3072 + h * 64 + l;
    float q[4], k[4], v[4];
#pragma unroll
    for (int t = 0; t < 4; ++t) {
        q[t] = b2f(QKV[rbase + t * 3072]);
        k[t] = b2f(QKV[rbase + t * 3072 + 1024]);
        v[t] = b2f(QKV[rbase + t * 3072 + 2048]);
    }
    const float scale = 0.03125f;         // C^-0.5 = 1/32 (d_model!)
    const size_t obase = (size_t)n * 4096 + h * 64 + l;
#pragma unroll
    for (int t = 0; t < 4; ++t) {
        float s0 = q[t] * k[0], s1 = q[t] * k[1], s2 = q[t] * k[2], s3 = q[t] * k[3];
#pragma unroll
        for (int o = 32; o; o >>= 1) {
            s0 += __shfl_xor(s0, o); s1 += __shfl_xor(s1, o);
            s2 += __shfl_xor(s2, o); s3 += __shfl_xor(s3, o);
        }
        s0 *= scale; s1 *= scale; s2 *= scale; s3 *= scale;
        const float m = fmaxf(fmaxf(s0, s1), fmaxf(s2, s3));
        const float e0 = expf(s0 - m), e1 = expf(s1 - m), e2 = expf(s2 - m), e3 = expf(s3 - m);
        const float inv = 1.f / (e0 + e1 + e2 + e3);
        const float o_ = (e0 * v[0] + e1 * v[1] + e2 * v[2] + e3 * v[3]) * inv;
        O[obase + t * 1024] = f2b(o_);
    }
}

// ---------- launch ----------
extern "C" void kernel_launch(void* const* d_in, const int* in_sizes, int n_in,
                              void* d_out, int out_size, void* d_ws, size_t ws_size,
                              hipStream_t stream)
{
    const float* x    = (const float*)d_in[0];
    const float* ln1g = (const float*)d_in[1];
    const float* ln1b = (const float*)d_in[2];
    const float* Wq   = (const float*)d_in[3];
    const float* Wk   = (const float*)d_in[4];
    const float* Wv   = (const float*)d_in[5];
    const float* Wp   = (const float*)d_in[6];
    const float* bp   = (const float*)d_in[7];
    const float* ln2g = (const float*)d_in[8];
    const float* ln2b = (const float*)d_in[9];
    const float* W1   = (const float*)d_in[10];
    const float* b1   = (const float*)d_in[11];
    const float* W2   = (const float*)d_in[12];
    const float* b2   = (const float*)d_in[13];
    float* out = (float*)d_out;

    char* ws = (char*)d_ws;
    const size_t MB = 1024 * 1024;
    float* xw_f  = (float*)ws;                      // 64MB: xw fp32 -> xr in-place
    u16*   xw_b  = (u16*)(ws + 64 * MB);            // 32MB: xw bf16, later att
    u16*   qkv   = (u16*)(ws + 96 * MB);            // 96MB: merged q|k|v  [16384][3072]
    u16*   ln2bf = qkv;                             // reuse after attn consumed qkv
    u16*   h1b   = (u16*)(ws + 128 * MB);
    u16*   WqkvT = (u16*)(ws + 192 * MB);           // 6MB  [3072][1024]
    u16*   WpT   = (u16*)(ws + 198 * MB);           // 2MB
    u16*   W1T   = (u16*)(ws + 200 * MB);
    u16*   W2T   = (u16*)(ws + 202 * MB);

    hipFuncSetAttribute((const void*)gemm256<0>, hipFuncAttributeMaxDynamicSharedMemorySize, 131072);
    hipFuncSetAttribute((const void*)gemm256<1>, hipFuncAttributeMaxDynamicSharedMemorySize, 131072);
    hipFuncSetAttribute((const void*)gemm256<2>, hipFuncAttributeMaxDynamicSharedMemorySize, 131072);
    hipFuncSetAttribute((const void*)gemm256<3>, hipFuncAttributeMaxDynamicSharedMemorySize, 131072);

    const int M = 16384, K = 1024;
    dim3 tpb(32, 8);
    transpose_w<<<dim3(2, 32, 16), tpb, 0, stream>>>(Wq, WqkvT,               1024, 64);
    transpose_w<<<dim3(2, 32, 16), tpb, 0, stream>>>(Wk, WqkvT + (1u << 20),  1024, 64);
    transpose_w<<<dim3(2, 32, 16), tpb, 0, stream>>>(Wv, WqkvT + (2u << 20),  1024, 64);
    transpose_w<<<dim3(32, 32, 1), tpb, 0, stream>>>(Wp, WpT, 1024, 1024);
    transpose_w<<<dim3(32, 32, 1), tpb, 0, stream>>>(W1, W1T, 1024, 1024);
    transpose_w<<<dim3(32, 32, 1), tpb, 0, stream>>>(W2, W2T, 1024, 1024);

    ln_kernel<1, 1><<<16384, 256, 0, stream>>>(x, ln1g, ln1b, xw_f, xw_b);

    // qkv = xw @ [Wq|Wk|Wv]   (N=3072)
    gemm256<0><<<768, 512, 131072, stream>>>(xw_b, WqkvT, nullptr, nullptr, qkv, M, 3072, K, 12);

    attn_kernel<<<16384, 256, 0, stream>>>(qkv, xw_b);            // att -> xw_b

    // xr = att @ Wp + bp + xw   (in-place into xw_f)
    gemm256<1><<<256, 512, 131072, stream>>>(xw_b, WpT, bp, xw_f, xw_f, M, 1024, K, 4);

    ln_kernel<0, 0><<<16384, 256, 0, stream>>>(xw_f, ln2g, ln2b, nullptr, ln2bf);

    // h1 = gelu(ln2 @ W1 + b1)
    gemm256<2><<<256, 512, 131072, stream>>>(ln2bf, W1T, b1, nullptr, h1b, M, 1024, K, 4);

    // out[natrow] = h1 @ W2 + b2 + xr
    gemm256<3><<<256, 512, 131072, stream>>>(h1b, W2T, b2, xw_f, out, M, 1024, K, 4);
}

// Round 3
// 420.626 us; speedup vs baseline: 1.2347x; 1.0792x over previous
//
#include <hip/hip_runtime.h>
#include <math.h>

typedef unsigned short u16;
typedef unsigned int   u32;

using f32x4 = __attribute__((ext_vector_type(4))) float;
using s16x8 = __attribute__((ext_vector_type(8))) short;

// ---------- helpers ----------
__device__ __forceinline__ u16 f2b(float f) {           // fp32 -> bf16 RNE
    u32 u = __float_as_uint(f);
    u += 0x7FFFu + ((u >> 16) & 1u);
    return (u16)(u >> 16);
}
__device__ __forceinline__ float b2f(u16 u) { return __uint_as_float(((u32)u) << 16); }

// window-order row R -> natural token row (b*256 + i*16 + j)
__device__ __forceinline__ int natrow(int R) {
    int b = R >> 8, r8 = R & 255, w = r8 >> 2, t = r8 & 3;
    return (b << 8) + ((((w >> 3) << 1) + (t >> 1)) << 4) + ((w & 7) << 1) + (t & 1);
}

__device__ __forceinline__ void gll16(const void* g, void* l) {
    __builtin_amdgcn_global_load_lds(
        (const __attribute__((address_space(1))) void*)g,
        (__attribute__((address_space(3))) void*)l, 16, 0, 0);
}

// ---------- weight repack: [R][C] f32 -> [C][R] bf16 (batched over z) ----------
__global__ __launch_bounds__(256) void transpose_w(
    const float* __restrict__ in, u16* __restrict__ out, int R, int C)
{
    __shared__ float tile[32][33];
    const int z = blockIdx.z;
    in  += (size_t)z * R * C;
    out += (size_t)z * R * C;
    const int tx = threadIdx.x, ty = threadIdx.y;
    const int c  = blockIdx.x * 32 + tx;
    const int r0 = blockIdx.y * 32;
#pragma unroll
    for (int i = 0; i < 32; i += 8) tile[ty + i][tx] = in[(size_t)(r0 + ty + i) * C + c];
    __syncthreads();
    const int orow0 = blockIdx.x * 32;
    const int ocol  = r0 + tx;
#pragma unroll
    for (int i = 0; i < 32; i += 8)
        out[(size_t)(orow0 + ty + i) * R + ocol] = f2b(tile[tx][ty + i]);
}

// ---------- LayerNorm (optionally with window-partition gather) ----------
template<int MAP, int WF32>
__global__ __launch_bounds__(256) void ln_kernel(
    const float* __restrict__ X, const float* __restrict__ g, const float* __restrict__ bta,
    float* __restrict__ outF, u16* __restrict__ outB)
{
    const int R   = blockIdx.x;
    const int src = MAP ? natrow(R) : R;
    const float4 v = ((const float4*)(X + (size_t)src * 1024))[threadIdx.x];
    float s  = v.x + v.y + v.z + v.w;
    float s2 = v.x * v.x + v.y * v.y + v.z * v.z + v.w * v.w;
#pragma unroll
    for (int o = 32; o; o >>= 1) { s += __shfl_xor(s, o); s2 += __shfl_xor(s2, o); }
    __shared__ float red[8];
    const int w = threadIdx.x >> 6, l = threadIdx.x & 63;
    if (l == 0) { red[w] = s; red[w + 4] = s2; }
    __syncthreads();
    s  = red[0] + red[1] + red[2] + red[3];
    s2 = red[4] + red[5] + red[6] + red[7];
    const float mean = s * (1.f / 1024.f);
    const float var  = s2 * (1.f / 1024.f) - mean * mean;
    const float rinv = rsqrtf(var + 1e-5f);
    const float4 gv = ((const float4*)g)[threadIdx.x];
    const float4 bv = ((const float4*)bta)[threadIdx.x];
    const float y0 = (v.x - mean) * rinv * gv.x + bv.x;
    const float y1 = (v.y - mean) * rinv * gv.y + bv.y;
    const float y2 = (v.z - mean) * rinv * gv.z + bv.z;
    const float y3 = (v.w - mean) * rinv * gv.w + bv.w;
    if (WF32) ((float4*)(outF + (size_t)R * 1024))[threadIdx.x] = make_float4(y0, y1, y2, y3);
    ((ushort4*)(outB + (size_t)R * 1024))[threadIdx.x] =
        make_ushort4(f2b(y0), f2b(y1), f2b(y2), f2b(y3));
}

// ---------- 256x256 8-wave GEMM, BK=64, swizzled LDS, counted-vmcnt pipeline ----------
// C[M][N] = A[M][K](bf16) @ Bt[N][K](bf16)^T
// MODE 0: store bf16   MODE 1: +bias+resid -> f32   MODE 2: gelu(+bias) -> bf16
// MODE 3: +bias+resid -> f32 at permuted (natural) row
//
// LDS (128KB dynamic): A: [d][half][128 rows][128B] at d*32K + half*16K; B at +64KB.
// Swizzle (G4, 3-bit): phys_byte = lin_byte ^ ((row&7)<<4)  -- row stride is 128B =
// exactly 32 banks, so bank depends only on in-row offset; reads use slots kg*16,
// XOR by (row&7)<<4 spreads each quarter-wave over all 8 slots -> 2-way only (free).
// Writes stay linear (global_load_lds); source address pre-permuted by the same
// involution in 16B chunks: q = p ^ ((p>>3)&7).
// Stage order per tile t (issued during tile t-1 phases 0..3): A0,B0,A1,B1
// Quadrant per phase p: qm=p&1, qn=p>>1; vmcnt(4) ends each phase (see accounting).
template<int MODE>
__global__ __launch_bounds__(512, 2) void gemm256(
    const u16* __restrict__ A, const u16* __restrict__ Bt,
    const float* __restrict__ bias, const float* __restrict__ resid,
    void* __restrict__ Out, int M, int N, int K, int NB)
{
    extern __shared__ char lds[];
    const int NT = K >> 6;
    const int nblk = gridDim.x;
    // XCD-chunked swizzle: consecutive logical blocks (same A panel) on same XCD
    const int lb = (blockIdx.x & 7) * (nblk >> 3) + (blockIdx.x >> 3);
    const int mb = lb / NB, nb = lb - mb * NB;
    const int row0 = mb * 256, col0 = nb * 256;
    const int tid = threadIdx.x;
    const int w = tid >> 6, l = tid & 63;
    const int wr = w >> 2, wc = w & 3;
    const int lr = l & 15, kg = l >> 4;
    const int xs = (lr & 7) << 4;                 // 3-bit G4 swizzle for reads
    const int koff[2] = { (kg * 16) ^ xs, (64 + kg * 16) ^ xs };
    const int abase_l = wr * 8192 + lr * 128;     // per-lane A row offset in half
    const int bbase_l = wc * 4096 + lr * 128;     // per-lane B row offset in half

    f32x4 acc[2][2][4][2] = {};                   // [qm][qn][i][n]

    auto stage = [&](int ts, int item) {          // item: 0=A0 1=B0 2=A1 3=B1
        if (ts >= NT) return;
        const int d = ts & 1;
        const int isB = item & 1, h = item >> 1;
        char* lbase = lds + (isB ? 65536 : 0) + d * 32768 + h * 16384;
        const u16* gptr = isB ? Bt : A;
        const int blk0 = (isB ? col0 : row0) + h * 128;
#pragma unroll
        for (int j = 0; j < 2; ++j) {
            const int p = j * 512 + tid;          // physical 16B chunk
            const int q = p ^ ((p >> 3) & 7);     // logical chunk (involution)
            const int grow = blk0 + (q >> 3);
            const int gcol = ts * 64 + (q & 7) * 8;
            gll16(gptr + (size_t)grow * K + gcol, lbase + (j * 8 + w) * 1024);
        }
    };

    // prologue: tile 0 all items; A0,B0 must land (vmcnt(4)), A1,B1 may fly
    stage(0, 0); stage(0, 1); stage(0, 2); stage(0, 3);
    asm volatile("s_waitcnt vmcnt(4)" ::: "memory");
    __builtin_amdgcn_s_barrier();

    for (int t = 0; t < NT; ++t) {
        const int d = t & 1;
        const char* Ab = lds + d * 32768;
        const char* Bb = lds + 65536 + d * 32768;
#pragma unroll
        for (int p = 0; p < 4; ++p) {
            const int qm = p & 1, qn = p >> 1;
            s16x8 a[4][2], b[2][2];
#pragma unroll
            for (int kk = 0; kk < 2; ++kk) {
#pragma unroll
                for (int i = 0; i < 4; ++i)
                    a[i][kk] = *(const s16x8*)(Ab + qm * 16384 + abase_l + i * 2048 + koff[kk]);
#pragma unroll
                for (int n = 0; n < 2; ++n)
                    b[n][kk] = *(const s16x8*)(Bb + qn * 16384 + bbase_l + n * 2048 + koff[kk]);
            }
            stage(t + 1, p);                      // next tile, item p (other buffer)
            __builtin_amdgcn_sched_barrier(0);
            __builtin_amdgcn_s_barrier();
            asm volatile("s_waitcnt lgkmcnt(0)" ::: "memory");
            __builtin_amdgcn_sched_barrier(0);
            __builtin_amdgcn_s_setprio(1);
#pragma unroll
            for (int kk = 0; kk < 2; ++kk)
#pragma unroll
                for (int i = 0; i < 4; ++i)
#pragma unroll
                    for (int n = 0; n < 2; ++n)
                        acc[qm][qn][i][n] = __builtin_amdgcn_mfma_f32_16x16x32_bf16(
                            a[i][kk], b[n][kk], acc[qm][qn][i][n], 0, 0, 0);
            __builtin_amdgcn_s_setprio(0);
            __builtin_amdgcn_sched_barrier(0);
            if (t == NT - 1) {
                if (p == 0) { asm volatile("s_waitcnt vmcnt(0)" ::: "memory"); }
            } else {
                asm volatile("s_waitcnt vmcnt(4)" ::: "memory");
            }
            __builtin_amdgcn_s_barrier();
            __builtin_amdgcn_sched_barrier(0);
        }
    }

    // epilogue
#pragma unroll
    for (int qm = 0; qm < 2; ++qm)
#pragma unroll
    for (int i = 0; i < 4; ++i) {
        const int grb = row0 + qm * 128 + wr * 64 + i * 16 + kg * 4;
#pragma unroll
        for (int qn = 0; qn < 2; ++qn)
#pragma unroll
        for (int n = 0; n < 2; ++n) {
            const int gc = col0 + qn * 128 + wc * 32 + n * 16 + lr;
#pragma unroll
            for (int j = 0; j < 4; ++j) {
                const int gr = grb + j;
                const float v = acc[qm][qn][i][n][j];
                if (MODE == 0) {
                    ((u16*)Out)[(size_t)gr * N + gc] = f2b(v);
                } else if (MODE == 1) {
                    ((float*)Out)[(size_t)gr * N + gc] = v + bias[gc] + resid[(size_t)gr * N + gc];
                } else if (MODE == 2) {
                    const float tt = v + bias[gc];
                    ((u16*)Out)[(size_t)gr * N + gc] = f2b(0.5f * tt * (1.f + erff(tt * 0.70710678118f)));
                } else {
                    ((float*)Out)[(size_t)natrow(gr) * N + gc] = v + bias[gc] + resid[(size_t)gr * N + gc];
                }
            }
        }
    }
}

// ---------- tiny windowed attention on merged qkv [16384][3072] ----------
__global__ __launch_bounds__(256) void attn_kernel(
    const u16* __restrict__ QKV, u16* __restrict__ O)
{
    const int tid = threadIdx.x;
    const int w = tid >> 6, l = tid & 63;
    const int p = blockIdx.x * 4 + w;     // 65536 (n,h) pairs
    const int n = p >> 4, h = p & 15;
    const size_t rbase = (size_t)n * 4 * 3072 + h * 64 + l;
    float q[4], k[4], v[4];
#pragma unroll
    for (int t = 0; t < 4; ++t) {
        q[t] = b2f(QKV[rbase + t * 3072]);
        k[t] = b2f(QKV[rbase + t * 3072 + 1024]);
        v[t] = b2f(QKV[rbase + t * 3072 + 2048]);
    }
    const float scale = 0.03125f;         // C^-0.5 = 1/32 (d_model!)
    const size_t obase = (size_t)n * 4096 + h * 64 + l;
#pragma unroll
    for (int t = 0; t < 4; ++t) {
        float s0 = q[t] * k[0], s1 = q[t] * k[1], s2 = q[t] * k[2], s3 = q[t] * k[3];
#pragma unroll
        for (int o = 32; o; o >>= 1) {
            s0 += __shfl_xor(s0, o); s1 += __shfl_xor(s1, o);
            s2 += __shfl_xor(s2, o); s3 += __shfl_xor(s3, o);
        }
        s0 *= scale; s1 *= scale; s2 *= scale; s3 *= scale;
        const float m = fmaxf(fmaxf(s0, s1), fmaxf(s2, s3));
        const float e0 = expf(s0 - m), e1 = expf(s1 - m), e2 = expf(s2 - m), e3 = expf(s3 - m);
        const float inv = 1.f / (e0 + e1 + e2 + e3);
        const float o_ = (e0 * v[0] + e1 * v[1] + e2 * v[2] + e3 * v[3]) * inv;
        O[obase + t * 1024] = f2b(o_);
    }
}

// ---------- launch ----------
extern "C" void kernel_launch(void* const* d_in, const int* in_sizes, int n_in,
                              void* d_out, int out_size, void* d_ws, size_t ws_size,
                              hipStream_t stream)
{
    const float* x    = (const float*)d_in[0];
    const float* ln1g = (const float*)d_in[1];
    const float* ln1b = (const float*)d_in[2];
    const float* Wq   = (const float*)d_in[3];
    const float* Wk   = (const float*)d_in[4];
    const float* Wv   = (const float*)d_in[5];
    const float* Wp   = (const float*)d_in[6];
    const float* bp   = (const float*)d_in[7];
    const float* ln2g = (const float*)d_in[8];
    const float* ln2b = (const float*)d_in[9];
    const float* W1   = (const float*)d_in[10];
    const float* b1   = (const float*)d_in[11];
    const float* W2   = (const float*)d_in[12];
    const float* b2   = (const float*)d_in[13];
    float* out = (float*)d_out;

    char* ws = (char*)d_ws;
    const size_t MB = 1024 * 1024;
    float* xw_f  = (float*)ws;                      // 64MB: xw fp32 -> xr in-place
    u16*   xw_b  = (u16*)(ws + 64 * MB);            // 32MB: xw bf16, later att
    u16*   qkv   = (u16*)(ws + 96 * MB);            // 96MB: merged q|k|v  [16384][3072]
    u16*   ln2bf = qkv;                             // reuse after attn consumed qkv
    u16*   h1b   = (u16*)(ws + 128 * MB);
    u16*   WqkvT = (u16*)(ws + 192 * MB);           // 6MB  [3072][1024]
    u16*   WpT   = (u16*)(ws + 198 * MB);           // 2MB
    u16*   W1T   = (u16*)(ws + 200 * MB);
    u16*   W2T   = (u16*)(ws + 202 * MB);

    hipFuncSetAttribute((const void*)gemm256<0>, hipFuncAttributeMaxDynamicSharedMemorySize, 131072);
    hipFuncSetAttribute((const void*)gemm256<1>, hipFuncAttributeMaxDynamicSharedMemorySize, 131072);
    hipFuncSetAttribute((const void*)gemm256<2>, hipFuncAttributeMaxDynamicSharedMemorySize, 131072);
    hipFuncSetAttribute((const void*)gemm256<3>, hipFuncAttributeMaxDynamicSharedMemorySize, 131072);

    const int M = 16384, K = 1024;
    dim3 tpb(32, 8);
    transpose_w<<<dim3(2, 32, 16), tpb, 0, stream>>>(Wq, WqkvT,               1024, 64);
    transpose_w<<<dim3(2, 32, 16), tpb, 0, stream>>>(Wk, WqkvT + (1u << 20),  1024, 64);
    transpose_w<<<dim3(2, 32, 16), tpb, 0, stream>>>(Wv, WqkvT + (2u << 20),  1024, 64);
    transpose_w<<<dim3(32, 32, 1), tpb, 0, stream>>>(Wp, WpT, 1024, 1024);
    transpose_w<<<dim3(32, 32, 1), tpb, 0, stream>>>(W1, W1T, 1024, 1024);
    transpose_w<<<dim3(32, 32, 1), tpb, 0, stream>>>(W2, W2T, 1024, 1024);

    ln_kernel<1, 1><<<16384, 256, 0, stream>>>(x, ln1g, ln1b, xw_f, xw_b);

    // qkv = xw @ [Wq|Wk|Wv]   (N=3072)
    gemm256<0><<<768, 512, 131072, stream>>>(xw_b, WqkvT, nullptr, nullptr, qkv, M, 3072, K, 12);

    attn_kernel<<<16384, 256, 0, stream>>>(qkv, xw_b);            // att -> xw_b

    // xr = att @ Wp + bp + xw   (in-place into xw_f)
    gemm256<1><<<256, 512, 131072, stream>>>(xw_b, WpT, bp, xw_f, xw_f, M, 1024, K, 4);

    ln_kernel<0, 0><<<16384, 256, 0, stream>>>(xw_f, ln2g, ln2b, nullptr, ln2bf);

    // h1 = gelu(ln2 @ W1 + b1)
    gemm256<2><<<256, 512, 131072, stream>>>(ln2bf, W1T, b1, nullptr, h1b, M, 1024, K, 4);

    // out[natrow] = h1 @ W2 + b2 + xr
    gemm256<3><<<256, 512, 131072, stream>>>(h1b, W2T, b2, xw_f, out, M, 1024, K, 4);
}

// Round 4
// 376.156 us; speedup vs baseline: 1.3807x; 1.1182x over previous
//
#include <hip/hip_runtime.h>
#include <math.h>

typedef unsigned short u16;
typedef unsigned int   u32;

using f32x4 = __attribute__((ext_vector_type(4))) float;
using s16x8 = __attribute__((ext_vector_type(8))) short;

// ---------- helpers ----------
__device__ __forceinline__ u16 f2b(float f) {           // fp32 -> bf16 RNE
    u32 u = __float_as_uint(f);
    u += 0x7FFFu + ((u >> 16) & 1u);
    return (u16)(u >> 16);
}
__device__ __forceinline__ float b2f(u16 u) { return __uint_as_float(((u32)u) << 16); }

// window-order row R -> natural token row (b*256 + i*16 + j)
__device__ __forceinline__ int natrow(int R) {
    int b = R >> 8, r8 = R & 255, w = r8 >> 2, t = r8 & 3;
    return (b << 8) + ((((w >> 3) << 1) + (t >> 1)) << 4) + ((w & 7) << 1) + (t & 1);
}

__device__ __forceinline__ void gll16(const void* g, void* l) {
    __builtin_amdgcn_global_load_lds(
        (const __attribute__((address_space(1))) void*)g,
        (__attribute__((address_space(3))) void*)l, 16, 0, 0);
}

// ---------- weight repack: [R][C] f32 -> [C][R] bf16 ----------
// generic body; R,C compile-time via args (both multiples of 32)
__device__ __forceinline__ void transpose_body(
    const float* __restrict__ in, u16* __restrict__ out, int R, int C)
{
    __shared__ float tile[32][33];
    const int tx = threadIdx.x, ty = threadIdx.y;
    const int c  = blockIdx.x * 32 + tx;
    const int r0 = blockIdx.y * 32;
#pragma unroll
    for (int i = 0; i < 32; i += 8) tile[ty + i][tx] = in[(size_t)(r0 + ty + i) * C + c];
    __syncthreads();
    const int orow0 = blockIdx.x * 32;
    const int ocol  = r0 + tx;
#pragma unroll
    for (int i = 0; i < 32; i += 8)
        out[(size_t)(orow0 + ty + i) * R + ocol] = f2b(tile[tx][ty + i]);
}

// z in [0,48): Wq heads 0-15, Wk 16-31, Wv 32-47; each head [1024][64] -> [64][1024]
__global__ __launch_bounds__(256) void transpose_qkv(
    const float* __restrict__ Wq, const float* __restrict__ Wk,
    const float* __restrict__ Wv, u16* __restrict__ out)
{
    const int z = blockIdx.z;
    const float* in = (z < 16 ? Wq : z < 32 ? Wk : Wv) + (size_t)(z & 15) * 65536;
    transpose_body(in, out + (size_t)z * 65536, 1024, 64);
}

// z in [0,3): Wp, W1, W2; [1024][1024] -> [1024][1024]^T, outputs contiguous
__global__ __launch_bounds__(256) void transpose_pw(
    const float* __restrict__ Wp, const float* __restrict__ W1,
    const float* __restrict__ W2, u16* __restrict__ out)
{
    const int z = blockIdx.z;
    const float* in = z == 0 ? Wp : z == 1 ? W1 : W2;
    transpose_body(in, out + (size_t)z * 1048576, 1024, 1024);
}

// ---------- LayerNorm (optionally with window-partition gather) ----------
template<int MAP, int WF32>
__global__ __launch_bounds__(256) void ln_kernel(
    const float* __restrict__ X, const float* __restrict__ g, const float* __restrict__ bta,
    float* __restrict__ outF, u16* __restrict__ outB)
{
    const int R   = blockIdx.x;
    const int src = MAP ? natrow(R) : R;
    const float4 v = ((const float4*)(X + (size_t)src * 1024))[threadIdx.x];
    float s  = v.x + v.y + v.z + v.w;
    float s2 = v.x * v.x + v.y * v.y + v.z * v.z + v.w * v.w;
#pragma unroll
    for (int o = 32; o; o >>= 1) { s += __shfl_xor(s, o); s2 += __shfl_xor(s2, o); }
    __shared__ float red[8];
    const int w = threadIdx.x >> 6, l = threadIdx.x & 63;
    if (l == 0) { red[w] = s; red[w + 4] = s2; }
    __syncthreads();
    s  = red[0] + red[1] + red[2] + red[3];
    s2 = red[4] + red[5] + red[6] + red[7];
    const float mean = s * (1.f / 1024.f);
    const float var  = s2 * (1.f / 1024.f) - mean * mean;
    const float rinv = rsqrtf(var + 1e-5f);
    const float4 gv = ((const float4*)g)[threadIdx.x];
    const float4 bv = ((const float4*)bta)[threadIdx.x];
    const float y0 = (v.x - mean) * rinv * gv.x + bv.x;
    const float y1 = (v.y - mean) * rinv * gv.y + bv.y;
    const float y2 = (v.z - mean) * rinv * gv.z + bv.z;
    const float y3 = (v.w - mean) * rinv * gv.w + bv.w;
    if (WF32) ((float4*)(outF + (size_t)R * 1024))[threadIdx.x] = make_float4(y0, y1, y2, y3);
    ((ushort4*)(outB + (size_t)R * 1024))[threadIdx.x] =
        make_ushort4(f2b(y0), f2b(y1), f2b(y2), f2b(y3));
}

// ---------- 256x256 8-wave GEMM, BK=64, swizzled LDS, counted-vmcnt pipeline ----------
// C[M][N] = A[M][K](bf16, row stride LDA) @ Bt[N][K](bf16)^T
// MODE 0: store bf16                MODE 2: gelu(+bias) -> bf16
// MODE 3: +bias +f32 resid -> f32 at permuted (natural) row
// MODE 4: +bias +bf16 resid -> f32
//
// LDS (128KB): A [d][half][128 rows][128B] at d*32K+half*16K; B at +64KB.
// Swizzle (3-bit): phys_byte = lin_byte ^ ((row&7)<<4); gll sources pre-permuted
// by the same involution in 16B chunks: q = p ^ ((p>>3)&7).
// Snake quadrant order (qm,qn): (0,0)->(1,0)->(1,1)->(0,1); both A-frag sets
// stay in registers -> per-phase ds_reads 12/8/4/0 (was 12/12/12/12).
// Stage order per tile t+1 (issued at phases 0..3 of tile t): A0,B0,A1,B1.
// vmcnt(4) ends each phase: retires exactly the item the next phase first uses.
template<int MODE>
__global__ __launch_bounds__(512, 2) void gemm256(
    const u16* __restrict__ A, const u16* __restrict__ Bt,
    const float* __restrict__ bias, const void* __restrict__ resid,
    void* __restrict__ Out, int M, int N, int K, int LDA, int NB)
{
    extern __shared__ char lds[];
    const int NT = K >> 6;
    const int nblk = gridDim.x;
    const int lb = (blockIdx.x & 7) * (nblk >> 3) + (blockIdx.x >> 3);
    const int mb = lb / NB, nb = lb - mb * NB;
    const int row0 = mb * 256, col0 = nb * 256;
    const int tid = threadIdx.x;
    const int w = tid >> 6, l = tid & 63;
    const int wr = w >> 2, wc = w & 3;
    const int lr = l & 15, kg = l >> 4;
    const int xs = (lr & 7) << 4;                 // 3-bit swizzle for reads
    const int koff[2] = { (kg * 16) ^ xs, (64 + kg * 16) ^ xs };
    const int abase_l = wr * 8192 + lr * 128;
    const int bbase_l = wc * 4096 + lr * 128;

    f32x4 acc[2][2][4][2] = {};                   // [qm][qn][i][n]
    s16x8 a0[4][2], a1[4][2], b[2][2];

    auto stage = [&](int ts, int item) {          // item: 0=A0 1=B0 2=A1 3=B1
        if (ts >= NT) return;
        const int d = ts & 1;
        const int isB = item & 1, h = item >> 1;
        char* lbase = lds + (isB ? 65536 : 0) + d * 32768 + h * 16384;
        const u16* gptr = isB ? Bt : A;
        const int ld = isB ? K : LDA;
        const int blk0 = (isB ? col0 : row0) + h * 128;
#pragma unroll
        for (int j = 0; j < 2; ++j) {
            const int p = j * 512 + tid;
            const int q = p ^ ((p >> 3) & 7);     // involution, row-preserving
            const int grow = blk0 + (q >> 3);
            const int gcol = ts * 64 + (q & 7) * 8;
            gll16(gptr + (size_t)grow * ld + gcol, lbase + (j * 8 + w) * 1024);
        }
    };

#define LOAD_A(dst, qm) do { \
    _Pragma("unroll") for (int kk = 0; kk < 2; ++kk) \
    _Pragma("unroll") for (int i = 0; i < 4; ++i) \
        dst[i][kk] = *(const s16x8*)(Ab + (qm) * 16384 + abase_l + i * 2048 + koff[kk]); \
} while (0)
#define LOAD_B(qn) do { \
    _Pragma("unroll") for (int kk = 0; kk < 2; ++kk) \
    _Pragma("unroll") for (int n = 0; n < 2; ++n) \
        b[n][kk] = *(const s16x8*)(Bb + (qn) * 16384 + bbase_l + n * 2048 + koff[kk]); \
} while (0)
#define SYNC_PRE do { \
    __builtin_amdgcn_sched_barrier(0); \
    __builtin_amdgcn_s_barrier(); \
    asm volatile("s_waitcnt lgkmcnt(0)" ::: "memory"); \
    __builtin_amdgcn_sched_barrier(0); \
} while (0)
#define MFMA_Q(qm, qn, aa) do { \
    __builtin_amdgcn_s_setprio(1); \
    _Pragma("unroll") for (int kk = 0; kk < 2; ++kk) \
    _Pragma("unroll") for (int i = 0; i < 4; ++i) \
    _Pragma("unroll") for (int n = 0; n < 2; ++n) \
        acc[qm][qn][i][n] = __builtin_amdgcn_mfma_f32_16x16x32_bf16( \
            aa[i][kk], b[n][kk], acc[qm][qn][i][n], 0, 0, 0); \
    __builtin_amdgcn_s_setprio(0); \
    __builtin_amdgcn_sched_barrier(0); \
} while (0)
#define SYNC_POST(p) do { \
    if (t == NT - 1) { if ((p) == 0) asm volatile("s_waitcnt vmcnt(0)" ::: "memory"); } \
    else asm volatile("s_waitcnt vmcnt(4)" ::: "memory"); \
    __builtin_amdgcn_s_barrier(); \
    __builtin_amdgcn_sched_barrier(0); \
} while (0)

    // prologue: tile 0 all items; A0,B0 must land (vmcnt(4)); A1,B1 may fly
    stage(0, 0); stage(0, 1); stage(0, 2); stage(0, 3);
    asm volatile("s_waitcnt vmcnt(4)" ::: "memory");
    __builtin_amdgcn_s_barrier();

    for (int t = 0; t < NT; ++t) {
        const char* Ab = lds + (t & 1) * 32768;
        const char* Bb = lds + 65536 + (t & 1) * 32768;
        // phase 0: load A0,B0 -> Q(0,0)
        LOAD_A(a0, 0); LOAD_B(0);
        stage(t + 1, 0);
        SYNC_PRE; MFMA_Q(0, 0, a0); SYNC_POST(0);
        // phase 1: load A1 -> Q(1,0)
        LOAD_A(a1, 1);
        stage(t + 1, 1);
        SYNC_PRE; MFMA_Q(1, 0, a1); SYNC_POST(1);
        // phase 2: load B1 -> Q(1,1)
        LOAD_B(1);
        stage(t + 1, 2);
        SYNC_PRE; MFMA_Q(1, 1, a1); SYNC_POST(2);
        // phase 3: no loads -> Q(0,1)
        stage(t + 1, 3);
        SYNC_PRE; MFMA_Q(0, 1, a0); SYNC_POST(3);
    }
#undef LOAD_A
#undef LOAD_B
#undef SYNC_PRE
#undef MFMA_Q
#undef SYNC_POST

    // epilogue
#pragma unroll
    for (int qm = 0; qm < 2; ++qm)
#pragma unroll
    for (int i = 0; i < 4; ++i) {
        const int grb = row0 + qm * 128 + wr * 64 + i * 16 + kg * 4;
#pragma unroll
        for (int qn = 0; qn < 2; ++qn)
#pragma unroll
        for (int n = 0; n < 2; ++n) {
            const int gc = col0 + qn * 128 + wc * 32 + n * 16 + lr;
#pragma unroll
            for (int j = 0; j < 4; ++j) {
                const int gr = grb + j;
                const float v = acc[qm][qn][i][n][j];
                if (MODE == 0) {
                    ((u16*)Out)[(size_t)gr * N + gc] = f2b(v);
                } else if (MODE == 2) {
                    const float tt = v + bias[gc];
                    ((u16*)Out)[(size_t)gr * N + gc] = f2b(0.5f * tt * (1.f + erff(tt * 0.70710678118f)));
                } else if (MODE == 3) {
                    ((float*)Out)[(size_t)natrow(gr) * N + gc] =
                        v + bias[gc] + ((const float*)resid)[(size_t)gr * N + gc];
                } else {
                    ((float*)Out)[(size_t)gr * N + gc] =
                        v + bias[gc] + b2f(((const u16*)resid)[(size_t)gr * N + gc]);
                }
            }
        }
    }
}

// ---------- tiny windowed attention, IN-PLACE into q-columns of qkv ----------
__global__ __launch_bounds__(256) void attn_kernel(u16* __restrict__ QKV)
{
    const int tid = threadIdx.x;
    const int w = tid >> 6, l = tid & 63;
    const int p = blockIdx.x * 4 + w;     // 65536 (n,h) pairs
    const int n = p >> 4, h = p & 15;
    const size_t rbase = (size_t)n * 4 * 3072 + h * 64 + l;
    float q[4], k[4], v[4];
#pragma unroll
    for (int t = 0; t < 4; ++t) {
        q[t] = b2f(QKV[rbase + t * 3072]);
        k[t] = b2f(QKV[rbase + t * 3072 + 1024]);
        v[t] = b2f(QKV[rbase + t * 3072 + 2048]);
    }
    const float scale = 0.03125f;         // C^-0.5 = 1/32 (d_model!)
#pragma unroll
    for (int t = 0; t < 4; ++t) {
        float s0 = q[t] * k[0], s1 = q[t] * k[1], s2 = q[t] * k[2], s3 = q[t] * k[3];
#pragma unroll
        for (int o = 32; o; o >>= 1) {
            s0 += __shfl_xor(s0, o); s1 += __shfl_xor(s1, o);
            s2 += __shfl_xor(s2, o); s3 += __shfl_xor(s3, o);
        }
        s0 *= scale; s1 *= scale; s2 *= scale; s3 *= scale;
        const float m = fmaxf(fmaxf(s0, s1), fmaxf(s2, s3));
        const float e0 = expf(s0 - m), e1 = expf(s1 - m), e2 = expf(s2 - m), e3 = expf(s3 - m);
        const float inv = 1.f / (e0 + e1 + e2 + e3);
        const float o_ = (e0 * v[0] + e1 * v[1] + e2 * v[2] + e3 * v[3]) * inv;
        QKV[rbase + t * 3072] = f2b(o_);  // overwrite own q slot (wave-private)
    }
}

// ---------- launch ----------
extern "C" void kernel_launch(void* const* d_in, const int* in_sizes, int n_in,
                              void* d_out, int out_size, void* d_ws, size_t ws_size,
                              hipStream_t stream)
{
    const float* x    = (const float*)d_in[0];
    const float* ln1g = (const float*)d_in[1];
    const float* ln1b = (const float*)d_in[2];
    const float* Wq   = (const float*)d_in[3];
    const float* Wk   = (const float*)d_in[4];
    const float* Wv   = (const float*)d_in[5];
    const float* Wp   = (const float*)d_in[6];
    const float* bp   = (const float*)d_in[7];
    const float* ln2g = (const float*)d_in[8];
    const float* ln2b = (const float*)d_in[9];
    const float* W1   = (const float*)d_in[10];
    const float* b1   = (const float*)d_in[11];
    const float* W2   = (const float*)d_in[12];
    const float* b2   = (const float*)d_in[13];
    float* out = (float*)d_out;

    char* ws = (char*)d_ws;
    const size_t MB = 1024 * 1024;
    float* xr_f  = (float*)ws;                      // 64MB: xr f32 (written by proj)
    u16*   xw_b  = (u16*)(ws + 64 * MB);            // 32MB: ln1(x) windowed, bf16
    u16*   qkv   = (u16*)(ws + 96 * MB);            // 96MB: q|k|v; attn in-place -> att in q cols
    u16*   ln2bf = (u16*)(ws + 128 * MB);           // 32MB (k-col region free after proj)
    u16*   h1b   = (u16*)(ws + 160 * MB);           // 32MB
    u16*   WqkvT = (u16*)(ws + 192 * MB);           // 6MB [3072][1024]
    u16*   WpT   = (u16*)(ws + 198 * MB);           // 3 x 2MB contiguous
    u16*   W1T   = WpT + (1u << 20);
    u16*   W2T   = W1T + (1u << 20);

    hipFuncSetAttribute((const void*)gemm256<0>, hipFuncAttributeMaxDynamicSharedMemorySize, 131072);
    hipFuncSetAttribute((const void*)gemm256<2>, hipFuncAttributeMaxDynamicSharedMemorySize, 131072);
    hipFuncSetAttribute((const void*)gemm256<3>, hipFuncAttributeMaxDynamicSharedMemorySize, 131072);
    hipFuncSetAttribute((const void*)gemm256<4>, hipFuncAttributeMaxDynamicSharedMemorySize, 131072);

    const int M = 16384, K = 1024;
    dim3 tpb(32, 8);
    transpose_qkv<<<dim3(2, 32, 48), tpb, 0, stream>>>(Wq, Wk, Wv, WqkvT);
    transpose_pw <<<dim3(32, 32, 3), tpb, 0, stream>>>(Wp, W1, W2, WpT);

    ln_kernel<1, 0><<<16384, 256, 0, stream>>>(x, ln1g, ln1b, nullptr, xw_b);

    // qkv = xw @ [Wq|Wk|Wv]   (N=3072)
    gemm256<0><<<768, 512, 131072, stream>>>(xw_b, WqkvT, nullptr, nullptr, qkv, M, 3072, K, K, 12);

    attn_kernel<<<16384, 256, 0, stream>>>(qkv);   // att overwrites q columns

    // xr = att @ Wp + bp + xw(bf16)   -> f32
    gemm256<4><<<256, 512, 131072, stream>>>(qkv, WpT, bp, xw_b, xr_f, M, 1024, K, 3072, 4);

    ln_kernel<0, 0><<<16384, 256, 0, stream>>>(xr_f, ln2g, ln2b, nullptr, ln2bf);

    // h1 = gelu(ln2 @ W1 + b1)
    gemm256<2><<<256, 512, 131072, stream>>>(ln2bf, W1T, b1, nullptr, h1b, M, 1024, K, K, 4);

    // out[natrow] = h1 @ W2 + b2 + xr
    gemm256<3><<<256, 512, 131072, stream>>>(h1b, W2T, b2, xr_f, out, M, 1024, K, K, 4);
}

// Round 5
// 322.105 us; speedup vs baseline: 1.6124x; 1.1678x over previous
//
#include <hip/hip_runtime.h>
#include <math.h>

typedef unsigned short u16;
typedef unsigned int   u32;

using f32x4  = __attribute__((ext_vector_type(4))) float;
using s16x8  = __attribute__((ext_vector_type(8))) short;
using u16x8  = __attribute__((ext_vector_type(8))) unsigned short;

// ---------- helpers ----------
__device__ __forceinline__ u16 f2b(float f) {           // fp32 -> bf16 RNE
    u32 u = __float_as_uint(f);
    u += 0x7FFFu + ((u >> 16) & 1u);
    return (u16)(u >> 16);
}
__device__ __forceinline__ float b2f(u16 u) { return __uint_as_float(((u32)u) << 16); }

// window-order row R -> natural token row (b*256 + i*16 + j)
__device__ __forceinline__ int natrow(int R) {
    int b = R >> 8, r8 = R & 255, w = r8 >> 2, t = r8 & 3;
    return (b << 8) + ((((w >> 3) << 1) + (t >> 1)) << 4) + ((w & 7) << 1) + (t & 1);
}

__device__ __forceinline__ void gll16(const void* g, void* l) {
    __builtin_amdgcn_global_load_lds(
        (const __attribute__((address_space(1))) void*)g,
        (__attribute__((address_space(3))) void*)l, 16, 0, 0);
}

// ---------- weight repack: [R][C] f32 -> [C][R] bf16 ----------
__device__ __forceinline__ void transpose_body(
    const float* __restrict__ in, u16* __restrict__ out, int R, int C)
{
    __shared__ float tile[32][33];
    const int tx = threadIdx.x, ty = threadIdx.y;
    const int c  = blockIdx.x * 32 + tx;
    const int r0 = blockIdx.y * 32;
#pragma unroll
    for (int i = 0; i < 32; i += 8) tile[ty + i][tx] = in[(size_t)(r0 + ty + i) * C + c];
    __syncthreads();
    const int orow0 = blockIdx.x * 32;
    const int ocol  = r0 + tx;
#pragma unroll
    for (int i = 0; i < 32; i += 8)
        out[(size_t)(orow0 + ty + i) * R + ocol] = f2b(tile[tx][ty + i]);
}

// z in [0,48): Wq heads 0-15, Wk 16-31, Wv 32-47; each head [1024][64] -> [64][1024]
__global__ __launch_bounds__(256) void transpose_qkv(
    const float* __restrict__ Wq, const float* __restrict__ Wk,
    const float* __restrict__ Wv, u16* __restrict__ out)
{
    const int z = blockIdx.z;
    const float* in = (z < 16 ? Wq : z < 32 ? Wk : Wv) + (size_t)(z & 15) * 65536;
    transpose_body(in, out + (size_t)z * 65536, 1024, 64);
}

// z in [0,3): Wp, W1, W2; [1024][1024] -> transposed, outputs contiguous
__global__ __launch_bounds__(256) void transpose_pw(
    const float* __restrict__ Wp, const float* __restrict__ W1,
    const float* __restrict__ W2, u16* __restrict__ out)
{
    const int z = blockIdx.z;
    const float* in = z == 0 ? Wp : z == 1 ? W1 : W2;
    transpose_body(in, out + (size_t)z * 1048576, 1024, 1024);
}

// ---------- LayerNorm; MAP = window-gather rows, BIN = bf16 input ----------
template<int MAP, int BIN>
__global__ __launch_bounds__(256) void ln_kernel(
    const void* __restrict__ X, const float* __restrict__ g, const float* __restrict__ bta,
    u16* __restrict__ outB)
{
    const int R   = blockIdx.x;
    const int src = MAP ? natrow(R) : R;
    float x0, x1, x2, x3;
    if (BIN) {
        const ushort4 r = ((const ushort4*)((const u16*)X + (size_t)src * 1024))[threadIdx.x];
        x0 = b2f(r.x); x1 = b2f(r.y); x2 = b2f(r.z); x3 = b2f(r.w);
    } else {
        const float4 r = ((const float4*)((const float*)X + (size_t)src * 1024))[threadIdx.x];
        x0 = r.x; x1 = r.y; x2 = r.z; x3 = r.w;
    }
    float s  = x0 + x1 + x2 + x3;
    float s2 = x0 * x0 + x1 * x1 + x2 * x2 + x3 * x3;
#pragma unroll
    for (int o = 32; o; o >>= 1) { s += __shfl_xor(s, o); s2 += __shfl_xor(s2, o); }
    __shared__ float red[8];
    const int w = threadIdx.x >> 6, l = threadIdx.x & 63;
    if (l == 0) { red[w] = s; red[w + 4] = s2; }
    __syncthreads();
    s  = red[0] + red[1] + red[2] + red[3];
    s2 = red[4] + red[5] + red[6] + red[7];
    const float mean = s * (1.f / 1024.f);
    const float var  = s2 * (1.f / 1024.f) - mean * mean;
    const float rinv = rsqrtf(var + 1e-5f);
    const float4 gv = ((const float4*)g)[threadIdx.x];
    const float4 bv = ((const float4*)bta)[threadIdx.x];
    ((ushort4*)(outB + (size_t)R * 1024))[threadIdx.x] = make_ushort4(
        f2b((x0 - mean) * rinv * gv.x + bv.x), f2b((x1 - mean) * rinv * gv.y + bv.y),
        f2b((x2 - mean) * rinv * gv.z + bv.z), f2b((x3 - mean) * rinv * gv.w + bv.w));
}

// ---------- 256x256 8-wave GEMM, BK=64, swizzled LDS, deep counted-vmcnt ----------
// C[M][N] = A[M][K](bf16, row stride LDA) @ Bt[N][K](bf16)^T
// MODE 0: bf16            MODE 2: gelu(+bias) -> bf16
// MODE 3: +bias + bf16 resid -> f32 at natrow     MODE 5: +bias + bf16 resid -> bf16
//
// LDS (128KB): A [d][half][128 rows][128B] at d*32K+half*16K; B at +64KB.
// Swizzle (3-bit): phys_byte = lin_byte ^ ((row&7)<<4); gll sources pre-permuted
// by same involution in 16B chunks: q = p ^ ((p>>3)&7).
// Snake quadrants (0,0)->(1,0)->(1,1)->(0,1); ds_reads/phase 12/8/4/0.
// Deep staging: tile t+1 items A0,B0 issued in t.ph0; A1,B1 in t.ph1.
// Waits: end of ph0 and ph3 only, vmcnt(4) -- every awaited load is >=3 phases old.
template<int MODE>
__global__ __launch_bounds__(512, 2) void gemm256(
    const u16* __restrict__ A, const u16* __restrict__ Bt,
    const float* __restrict__ bias, const void* __restrict__ resid,
    void* __restrict__ Out, int M, int N, int K, int LDA, int NB)
{
    extern __shared__ char lds[];
    const int NT = K >> 6;
    const int nblk = gridDim.x;
    const int lb = (blockIdx.x & 7) * (nblk >> 3) + (blockIdx.x >> 3);
    const int mb = lb / NB, nb = lb - mb * NB;
    const int row0 = mb * 256, col0 = nb * 256;
    const int tid = threadIdx.x;
    const int w = tid >> 6, l = tid & 63;
    const int wr = w >> 2, wc = w & 3;
    const int lr = l & 15, kg = l >> 4;
    const int xs = (lr & 7) << 4;
    const int koff[2] = { (kg * 16) ^ xs, (64 + kg * 16) ^ xs };
    const int abase_l = wr * 8192 + lr * 128;
    const int bbase_l = wc * 4096 + lr * 128;

    f32x4 acc[2][2][4][2] = {};                   // [qm][qn][i][n]
    s16x8 a0[4][2], a1[4][2], b[2][2];

    auto stage = [&](int ts, int item) {          // item: 0=A0 1=B0 2=A1 3=B1
        if (ts >= NT) return;
        const int d = ts & 1;
        const int isB = item & 1, h = item >> 1;
        char* lbase = lds + (isB ? 65536 : 0) + d * 32768 + h * 16384;
        const u16* gptr = isB ? Bt : A;
        const int ld = isB ? K : LDA;
        const int blk0 = (isB ? col0 : row0) + h * 128;
#pragma unroll
        for (int j = 0; j < 2; ++j) {
            const int p = j * 512 + tid;
            const int q = p ^ ((p >> 3) & 7);     // involution, row-preserving
            const int grow = blk0 + (q >> 3);
            const int gcol = ts * 64 + (q & 7) * 8;
            gll16(gptr + (size_t)grow * ld + gcol, lbase + (j * 8 + w) * 1024);
        }
    };

#define LOAD_A(dst, qm) do { \
    _Pragma("unroll") for (int kk = 0; kk < 2; ++kk) \
    _Pragma("unroll") for (int i = 0; i < 4; ++i) \
        dst[i][kk] = *(const s16x8*)(Ab + (qm) * 16384 + abase_l + i * 2048 + koff[kk]); \
} while (0)
#define LOAD_B(qn) do { \
    _Pragma("unroll") for (int kk = 0; kk < 2; ++kk) \
    _Pragma("unroll") for (int n = 0; n < 2; ++n) \
        b[n][kk] = *(const s16x8*)(Bb + (qn) * 16384 + bbase_l + n * 2048 + koff[kk]); \
} while (0)
#define SYNC_PRE do { \
    __builtin_amdgcn_sched_barrier(0); \
    __builtin_amdgcn_s_barrier(); \
    asm volatile("s_waitcnt lgkmcnt(0)" ::: "memory"); \
    __builtin_amdgcn_sched_barrier(0); \
} while (0)
#define MFMA_Q(qm, qn, aa) do { \
    __builtin_amdgcn_s_setprio(1); \
    _Pragma("unroll") for (int kk = 0; kk < 2; ++kk) \
    _Pragma("unroll") for (int i = 0; i < 4; ++i) \
    _Pragma("unroll") for (int n = 0; n < 2; ++n) \
        acc[qm][qn][i][n] = __builtin_amdgcn_mfma_f32_16x16x32_bf16( \
            aa[i][kk], b[n][kk], acc[qm][qn][i][n], 0, 0, 0); \
    __builtin_amdgcn_s_setprio(0); \
    __builtin_amdgcn_sched_barrier(0); \
} while (0)
#define SYNC_POST(p) do { \
    if ((p) == 0) { \
        if (t == NT - 1) asm volatile("s_waitcnt vmcnt(0)" ::: "memory"); \
        else            asm volatile("s_waitcnt vmcnt(4)" ::: "memory"); \
    } else if ((p) == 3 && t < NT - 1) { \
        asm volatile("s_waitcnt vmcnt(4)" ::: "memory"); \
    } \
    __builtin_amdgcn_s_barrier(); \
    __builtin_amdgcn_sched_barrier(0); \
} while (0)

    // prologue: tile 0 all items; A0,B0 must land; A1,B1 may fly
    stage(0, 0); stage(0, 1); stage(0, 2); stage(0, 3);
    asm volatile("s_waitcnt vmcnt(4)" ::: "memory");
    __builtin_amdgcn_s_barrier();

    for (int t = 0; t < NT; ++t) {
        const char* Ab = lds + (t & 1) * 32768;
        const char* Bb = lds + 65536 + (t & 1) * 32768;
        // phase 0: read A0,B0; stage next A0,B0 -> Q(0,0)
        LOAD_A(a0, 0); LOAD_B(0);
        stage(t + 1, 0); stage(t + 1, 1);
        SYNC_PRE; MFMA_Q(0, 0, a0); SYNC_POST(0);
        // phase 1: read A1; stage next A1,B1 -> Q(1,0)
        LOAD_A(a1, 1);
        stage(t + 1, 2); stage(t + 1, 3);
        SYNC_PRE; MFMA_Q(1, 0, a1); SYNC_POST(1);
        // phase 2: read B1 -> Q(1,1)
        LOAD_B(1);
        SYNC_PRE; MFMA_Q(1, 1, a1); SYNC_POST(2);
        // phase 3: no reads, no stage -> Q(0,1)
        MFMA_Q(0, 1, a0); SYNC_POST(3);
    }
#undef LOAD_A
#undef LOAD_B
#undef SYNC_PRE
#undef MFMA_Q
#undef SYNC_POST

    // epilogue
#pragma unroll
    for (int qm = 0; qm < 2; ++qm)
#pragma unroll
    for (int i = 0; i < 4; ++i) {
        const int grb = row0 + qm * 128 + wr * 64 + i * 16 + kg * 4;
#pragma unroll
        for (int qn = 0; qn < 2; ++qn)
#pragma unroll
        for (int n = 0; n < 2; ++n) {
            const int gc = col0 + qn * 128 + wc * 32 + n * 16 + lr;
#pragma unroll
            for (int j = 0; j < 4; ++j) {
                const int gr = grb + j;
                const float v = acc[qm][qn][i][n][j];
                if (MODE == 0) {
                    ((u16*)Out)[(size_t)gr * N + gc] = f2b(v);
                } else if (MODE == 2) {
                    const float tt = v + bias[gc];
                    ((u16*)Out)[(size_t)gr * N + gc] = f2b(0.5f * tt * (1.f + erff(tt * 0.70710678118f)));
                } else if (MODE == 3) {
                    ((float*)Out)[(size_t)natrow(gr) * N + gc] =
                        v + bias[gc] + b2f(((const u16*)resid)[(size_t)gr * N + gc]);
                } else {
                    ((u16*)Out)[(size_t)gr * N + gc] =
                        f2b(v + bias[gc] + b2f(((const u16*)resid)[(size_t)gr * N + gc]));
                }
            }
        }
    }
}

// ---------- tiny windowed attention, vectorized short8, in-place into q cols ----------
// one wave per window; lane l, chunk c covers cols c*512 + l*8 (head = c*8 + (l>>3))
__global__ __launch_bounds__(256) void attn_kernel(u16* __restrict__ QKV)
{
    const int w = threadIdx.x >> 6, l = threadIdx.x & 63;
    const int n = blockIdx.x * 4 + w;             // 4096 windows
    u16* base = QKV + (size_t)n * 4 * 3072;
    const float scale = 0.03125f;                 // C^-0.5 = 1/32 (d_model!)
#pragma unroll
    for (int c = 0; c < 2; ++c) {
        const int col = c * 512 + l * 8;
        u16x8 qr[4], kr[4], vr[4];
#pragma unroll
        for (int t = 0; t < 4; ++t) {
            qr[t] = *(const u16x8*)(base + t * 3072 + col);
            kr[t] = *(const u16x8*)(base + t * 3072 + 1024 + col);
            vr[t] = *(const u16x8*)(base + t * 3072 + 2048 + col);
        }
        float qf[4][8], kf[4][8];
#pragma unroll
        for (int t = 0; t < 4; ++t)
#pragma unroll
            for (int j = 0; j < 8; ++j) { qf[t][j] = b2f(qr[t][j]); kf[t][j] = b2f(kr[t][j]); }
        float s[4][4];
#pragma unroll
        for (int t = 0; t < 4; ++t)
#pragma unroll
            for (int u = 0; u < 4; ++u) {
                float p = qf[t][0] * kf[u][0];
#pragma unroll
                for (int j = 1; j < 8; ++j) p += qf[t][j] * kf[u][j];
                p += __shfl_xor(p, 1); p += __shfl_xor(p, 2); p += __shfl_xor(p, 4);
                s[t][u] = p * scale;              // per-head dot (8-lane group)
            }
#pragma unroll
        for (int t = 0; t < 4; ++t) {
            const float m = fmaxf(fmaxf(s[t][0], s[t][1]), fmaxf(s[t][2], s[t][3]));
            const float e0 = expf(s[t][0] - m), e1 = expf(s[t][1] - m);
            const float e2 = expf(s[t][2] - m), e3 = expf(s[t][3] - m);
            const float inv = 1.f / (e0 + e1 + e2 + e3);
            u16x8 o;
#pragma unroll
            for (int j = 0; j < 8; ++j)
                o[j] = f2b((e0 * b2f(vr[0][j]) + e1 * b2f(vr[1][j]) +
                            e2 * b2f(vr[2][j]) + e3 * b2f(vr[3][j])) * inv);
            *(u16x8*)(base + t * 3072 + col) = o; // overwrite own q slot (wave-private)
        }
    }
}

// ---------- launch ----------
extern "C" void kernel_launch(void* const* d_in, const int* in_sizes, int n_in,
                              void* d_out, int out_size, void* d_ws, size_t ws_size,
                              hipStream_t stream)
{
    const float* x    = (const float*)d_in[0];
    const float* ln1g = (const float*)d_in[1];
    const float* ln1b = (const float*)d_in[2];
    const float* Wq   = (const float*)d_in[3];
    const float* Wk   = (const float*)d_in[4];
    const float* Wv   = (const float*)d_in[5];
    const float* Wp   = (const float*)d_in[6];
    const float* bp   = (const float*)d_in[7];
    const float* ln2g = (const float*)d_in[8];
    const float* ln2b = (const float*)d_in[9];
    const float* W1   = (const float*)d_in[10];
    const float* b1   = (const float*)d_in[11];
    const float* W2   = (const float*)d_in[12];
    const float* b2   = (const float*)d_in[13];
    float* out = (float*)d_out;

    char* ws = (char*)d_ws;
    const size_t MB = 1024 * 1024;
    u16* xr_b  = (u16*)ws;                        // 32MB: xr bf16 (residual spine)
    u16* xw_b  = (u16*)(ws + 32 * MB);            // 32MB: ln1(x) windowed bf16
    u16* qkv   = (u16*)(ws + 64 * MB);            // 96MB: q|k|v; attn in-place; dead after proj
    u16* h1b   = (u16*)(ws + 64 * MB);            // 32MB: reuse of qkv region after proj
    u16* ln2bf = (u16*)(ws + 160 * MB);           // 32MB
    u16* WqkvT = (u16*)(ws + 192 * MB);           // 6MB [3072][1024]
    u16* WpT   = (u16*)(ws + 198 * MB);           // 3 x 2MB contiguous
    u16* W1T   = WpT + (1u << 20);
    u16* W2T   = W1T + (1u << 20);

    hipFuncSetAttribute((const void*)gemm256<0>, hipFuncAttributeMaxDynamicSharedMemorySize, 131072);
    hipFuncSetAttribute((const void*)gemm256<2>, hipFuncAttributeMaxDynamicSharedMemorySize, 131072);
    hipFuncSetAttribute((const void*)gemm256<3>, hipFuncAttributeMaxDynamicSharedMemorySize, 131072);
    hipFuncSetAttribute((const void*)gemm256<5>, hipFuncAttributeMaxDynamicSharedMemorySize, 131072);

    const int M = 16384, K = 1024;
    dim3 tpb(32, 8);
    transpose_qkv<<<dim3(2, 32, 48), tpb, 0, stream>>>(Wq, Wk, Wv, WqkvT);
    transpose_pw <<<dim3(32, 32, 3), tpb, 0, stream>>>(Wp, W1, W2, WpT);

    ln_kernel<1, 0><<<16384, 256, 0, stream>>>(x, ln1g, ln1b, xw_b);

    // qkv = xw @ [Wq|Wk|Wv]   (N=3072)
    gemm256<0><<<768, 512, 131072, stream>>>(xw_b, WqkvT, nullptr, nullptr, qkv, M, 3072, K, K, 12);

    attn_kernel<<<1024, 256, 0, stream>>>(qkv);    // att overwrites q columns

    // xr = att @ Wp + bp + xw  -> bf16 spine
    gemm256<5><<<256, 512, 131072, stream>>>(qkv, WpT, bp, xw_b, xr_b, M, 1024, K, 3072, 4);

    ln_kernel<0, 1><<<16384, 256, 0, stream>>>(xr_b, ln2g, ln2b, ln2bf);

    // h1 = gelu(ln2 @ W1 + b1)   (qkv region is dead now -> h1b)
    gemm256<2><<<256, 512, 131072, stream>>>(ln2bf, W1T, b1, nullptr, h1b, M, 1024, K, K, 4);

    // out[natrow] = h1 @ W2 + b2 + xr
    gemm256<3><<<256, 512, 131072, stream>>>(h1b, W2T, b2, xr_b, out, M, 1024, K, K, 4);
}

// Round 6
// 312.766 us; speedup vs baseline: 1.6606x; 1.0299x over previous
//
#include <hip/hip_runtime.h>
#include <math.h>

typedef unsigned short u16;
typedef unsigned int   u32;

using f32x4  = __attribute__((ext_vector_type(4))) float;
using s16x8  = __attribute__((ext_vector_type(8))) short;
using u16x8  = __attribute__((ext_vector_type(8))) unsigned short;

// ---------- helpers ----------
__device__ __forceinline__ u16 f2b(float f) {           // fp32 -> bf16 RNE
    u32 u = __float_as_uint(f);
    u += 0x7FFFu + ((u >> 16) & 1u);
    return (u16)(u >> 16);
}
__device__ __forceinline__ float b2f(u16 u) { return __uint_as_float(((u32)u) << 16); }

// window-order row R -> natural token row (b*256 + i*16 + j)
__device__ __forceinline__ int natrow(int R) {
    int b = R >> 8, r8 = R & 255, w = r8 >> 2, t = r8 & 3;
    return (b << 8) + ((((w >> 3) << 1) + (t >> 1)) << 4) + ((w & 7) << 1) + (t & 1);
}

__device__ __forceinline__ void gll16(const void* g, void* l) {
    __builtin_amdgcn_global_load_lds(
        (const __attribute__((address_space(1))) void*)g,
        (__attribute__((address_space(3))) void*)l, 16, 0, 0);
}

// ---------- weight repack: [R][C] f32 -> [C][R] bf16 ----------
__device__ __forceinline__ void transpose_body(
    const float* __restrict__ in, u16* __restrict__ out, int R, int C)
{
    __shared__ float tile[32][33];
    const int tx = threadIdx.x, ty = threadIdx.y;
    const int c  = blockIdx.x * 32 + tx;
    const int r0 = blockIdx.y * 32;
#pragma unroll
    for (int i = 0; i < 32; i += 8) tile[ty + i][tx] = in[(size_t)(r0 + ty + i) * C + c];
    __syncthreads();
    const int orow0 = blockIdx.x * 32;
    const int ocol  = r0 + tx;
#pragma unroll
    for (int i = 0; i < 32; i += 8)
        out[(size_t)(orow0 + ty + i) * R + ocol] = f2b(tile[tx][ty + i]);
}

// z in [0,48): Wq heads 0-15, Wk 16-31, Wv 32-47; each head [1024][64] -> [64][1024]
__global__ __launch_bounds__(256) void transpose_qkv(
    const float* __restrict__ Wq, const float* __restrict__ Wk,
    const float* __restrict__ Wv, u16* __restrict__ out)
{
    const int z = blockIdx.z;
    const float* in = (z < 16 ? Wq : z < 32 ? Wk : Wv) + (size_t)(z & 15) * 65536;
    transpose_body(in, out + (size_t)z * 65536, 1024, 64);
}

// z in [0,3): Wp, W1, W2; [1024][1024] -> transposed, outputs contiguous
__global__ __launch_bounds__(256) void transpose_pw(
    const float* __restrict__ Wp, const float* __restrict__ W1,
    const float* __restrict__ W2, u16* __restrict__ out)
{
    const int z = blockIdx.z;
    const float* in = z == 0 ? Wp : z == 1 ? W1 : W2;
    transpose_body(in, out + (size_t)z * 1048576, 1024, 1024);
}

// ---------- LayerNorm; MAP = window-gather rows, BIN = bf16 input ----------
template<int MAP, int BIN>
__global__ __launch_bounds__(256) void ln_kernel(
    const void* __restrict__ X, const float* __restrict__ g, const float* __restrict__ bta,
    u16* __restrict__ outB)
{
    const int R   = blockIdx.x;
    const int src = MAP ? natrow(R) : R;
    float x0, x1, x2, x3;
    if (BIN) {
        const ushort4 r = ((const ushort4*)((const u16*)X + (size_t)src * 1024))[threadIdx.x];
        x0 = b2f(r.x); x1 = b2f(r.y); x2 = b2f(r.z); x3 = b2f(r.w);
    } else {
        const float4 r = ((const float4*)((const float*)X + (size_t)src * 1024))[threadIdx.x];
        x0 = r.x; x1 = r.y; x2 = r.z; x3 = r.w;
    }
    float s  = x0 + x1 + x2 + x3;
    float s2 = x0 * x0 + x1 * x1 + x2 * x2 + x3 * x3;
#pragma unroll
    for (int o = 32; o; o >>= 1) { s += __shfl_xor(s, o); s2 += __shfl_xor(s2, o); }
    __shared__ float red[8];
    const int w = threadIdx.x >> 6, l = threadIdx.x & 63;
    if (l == 0) { red[w] = s; red[w + 4] = s2; }
    __syncthreads();
    s  = red[0] + red[1] + red[2] + red[3];
    s2 = red[4] + red[5] + red[6] + red[7];
    const float mean = s * (1.f / 1024.f);
    const float var  = s2 * (1.f / 1024.f) - mean * mean;
    const float rinv = rsqrtf(var + 1e-5f);
    const float4 gv = ((const float4*)g)[threadIdx.x];
    const float4 bv = ((const float4*)bta)[threadIdx.x];
    ((ushort4*)(outB + (size_t)R * 1024))[threadIdx.x] = make_ushort4(
        f2b((x0 - mean) * rinv * gv.x + bv.x), f2b((x1 - mean) * rinv * gv.y + bv.y),
        f2b((x2 - mean) * rinv * gv.z + bv.z), f2b((x3 - mean) * rinv * gv.w + bv.w));
}

// ---------- 256x256 8-wave GEMM, BK=64, swizzled LDS, 1-barrier-per-tile ----------
// C[M][N] = A[M][K](bf16, row stride LDA) @ Bt[N][K](bf16)^T
// MODE 0: bf16            MODE 2: gelu(+bias) -> bf16
// MODE 3: +bias + bf16 resid -> f32 at natrow     MODE 5: +bias + bf16 resid -> bf16
//
// LDS (128KB): A [d][half][128 rows][128B] at d*32K+half*16K; B at +64KB.
// Swizzle (3-bit): phys_byte = lin_byte ^ ((row&7)<<4); gll sources pre-permuted
// by same involution in 16B chunks: q = p ^ ((p>>3)&7).
//
// Per tile: all 24 ds_reads issued up-front in pinned groups (a0+b0 | a1 | b1),
// then 8 next-tile gll stages; counted lgkmcnt(12)/(4)/(0) lets Q(0,0) start as
// soon as its fragments land while a1/b1 reads drain under the MFMAs.
// ONE barrier + ONE vmcnt(0) per tile (tile-end). Safety invariant: each wave's
// last ds_read completes at its lgkmcnt(0) (pre-Q(1,1)), strictly before the
// tile-end barrier -> post-barrier stage DMAs into the opposite buffer can
// never clobber in-flight reads. Tile-end vmcnt(0) targets loads issued at
// tile start (~2400 cyc earlier): HBM latency covered.
template<int MODE>
__global__ __launch_bounds__(512, 2) void gemm256(
    const u16* __restrict__ A, const u16* __restrict__ Bt,
    const float* __restrict__ bias, const void* __restrict__ resid,
    void* __restrict__ Out, int M, int N, int K, int LDA, int NB)
{
    extern __shared__ char lds[];
    const int NT = K >> 6;
    const int nblk = gridDim.x;
    const int lb = (blockIdx.x & 7) * (nblk >> 3) + (blockIdx.x >> 3);
    const int mb = lb / NB, nb = lb - mb * NB;
    const int row0 = mb * 256, col0 = nb * 256;
    const int tid = threadIdx.x;
    const int w = tid >> 6, l = tid & 63;
    const int wr = w >> 2, wc = w & 3;
    const int lr = l & 15, kg = l >> 4;
    const int xs = (lr & 7) << 4;
    const int koff[2] = { (kg * 16) ^ xs, (64 + kg * 16) ^ xs };
    const int abase_l = wr * 8192 + lr * 128;
    const int bbase_l = wc * 4096 + lr * 128;

    f32x4 acc[2][2][4][2] = {};                   // [qm][qn][i][n]
    s16x8 a0[4][2], a1[4][2], b0[2][2], b1[2][2];

    auto stage = [&](int ts, int item) {          // item: 0=A0 1=B0 2=A1 3=B1
        if (ts >= NT) return;
        const int d = ts & 1;
        const int isB = item & 1, h = item >> 1;
        char* lbase = lds + (isB ? 65536 : 0) + d * 32768 + h * 16384;
        const u16* gptr = isB ? Bt : A;
        const int ld = isB ? K : LDA;
        const int blk0 = (isB ? col0 : row0) + h * 128;
#pragma unroll
        for (int j = 0; j < 2; ++j) {
            const int p = j * 512 + tid;
            const int q = p ^ ((p >> 3) & 7);     // involution, row-preserving
            const int grow = blk0 + (q >> 3);
            const int gcol = ts * 64 + (q & 7) * 8;
            gll16(gptr + (size_t)grow * ld + gcol, lbase + (j * 8 + w) * 1024);
        }
    };

#define LOAD_A(dst, qm) do { \
    _Pragma("unroll") for (int kk = 0; kk < 2; ++kk) \
    _Pragma("unroll") for (int i = 0; i < 4; ++i) \
        dst[i][kk] = *(const s16x8*)(Ab + (qm) * 16384 + abase_l + i * 2048 + koff[kk]); \
} while (0)
#define LOAD_B(dst, qn) do { \
    _Pragma("unroll") for (int kk = 0; kk < 2; ++kk) \
    _Pragma("unroll") for (int n = 0; n < 2; ++n) \
        dst[n][kk] = *(const s16x8*)(Bb + (qn) * 16384 + bbase_l + n * 2048 + koff[kk]); \
} while (0)
#define MFMA_Q(qm, qn, aa, bb) do { \
    __builtin_amdgcn_s_setprio(1); \
    _Pragma("unroll") for (int kk = 0; kk < 2; ++kk) \
    _Pragma("unroll") for (int i = 0; i < 4; ++i) \
    _Pragma("unroll") for (int n = 0; n < 2; ++n) \
        acc[qm][qn][i][n] = __builtin_amdgcn_mfma_f32_16x16x32_bf16( \
            aa[i][kk], bb[n][kk], acc[qm][qn][i][n], 0, 0, 0); \
    __builtin_amdgcn_s_setprio(0); \
    __builtin_amdgcn_sched_barrier(0); \
} while (0)
#define WAIT_LGKM(n) do { \
    asm volatile("s_waitcnt lgkmcnt(" #n ")" ::: "memory"); \
    __builtin_amdgcn_sched_barrier(0); \
} while (0)

    // prologue: stage tile 0, drain, barrier
    stage(0, 0); stage(0, 1); stage(0, 2); stage(0, 3);
    asm volatile("s_waitcnt vmcnt(0)" ::: "memory");
    __builtin_amdgcn_s_barrier();

    for (int t = 0; t < NT; ++t) {
        const char* Ab = lds + (t & 1) * 32768;
        const char* Bb = lds + 65536 + (t & 1) * 32768;
        // group 1: a0 + b0 (12 ds_reads)
        LOAD_A(a0, 0); LOAD_B(b0, 0);
        __builtin_amdgcn_sched_barrier(0);
        // group 2: a1 (8 ds_reads)
        LOAD_A(a1, 1);
        __builtin_amdgcn_sched_barrier(0);
        // group 3: b1 (4 ds_reads)
        LOAD_B(b1, 1);
        __builtin_amdgcn_sched_barrier(0);
        // next-tile stages (8 vmem, other buffer)
        stage(t + 1, 0); stage(t + 1, 1); stage(t + 1, 2); stage(t + 1, 3);
        __builtin_amdgcn_sched_barrier(0);
        WAIT_LGKM(12);                 // a0,b0 landed
        MFMA_Q(0, 0, a0, b0);
        WAIT_LGKM(4);                  // a1 landed
        MFMA_Q(1, 0, a1, b0);
        WAIT_LGKM(0);                  // b1 landed
        MFMA_Q(1, 1, a1, b1);
        MFMA_Q(0, 1, a0, b1);
        if (t < NT - 1) {
            asm volatile("s_waitcnt vmcnt(0)" ::: "memory");
            __builtin_amdgcn_s_barrier();
            __builtin_amdgcn_sched_barrier(0);
        }
    }
#undef LOAD_A
#undef LOAD_B
#undef MFMA_Q
#undef WAIT_LGKM

    // epilogue
#pragma unroll
    for (int qm = 0; qm < 2; ++qm)
#pragma unroll
    for (int i = 0; i < 4; ++i) {
        const int grb = row0 + qm * 128 + wr * 64 + i * 16 + kg * 4;
#pragma unroll
        for (int qn = 0; qn < 2; ++qn)
#pragma unroll
        for (int n = 0; n < 2; ++n) {
            const int gc = col0 + qn * 128 + wc * 32 + n * 16 + lr;
#pragma unroll
            for (int j = 0; j < 4; ++j) {
                const int gr = grb + j;
                const float v = acc[qm][qn][i][n][j];
                if (MODE == 0) {
                    ((u16*)Out)[(size_t)gr * N + gc] = f2b(v);
                } else if (MODE == 2) {
                    const float tt = v + bias[gc];
                    ((u16*)Out)[(size_t)gr * N + gc] = f2b(0.5f * tt * (1.f + erff(tt * 0.70710678118f)));
                } else if (MODE == 3) {
                    ((float*)Out)[(size_t)natrow(gr) * N + gc] =
                        v + bias[gc] + b2f(((const u16*)resid)[(size_t)gr * N + gc]);
                } else {
                    ((u16*)Out)[(size_t)gr * N + gc] =
                        f2b(v + bias[gc] + b2f(((const u16*)resid)[(size_t)gr * N + gc]));
                }
            }
        }
    }
}

// ---------- tiny windowed attention, vectorized short8, in-place into q cols ----------
// one wave per window; lane l, chunk c covers cols c*512 + l*8 (head = c*8 + (l>>3))
__global__ __launch_bounds__(256) void attn_kernel(u16* __restrict__ QKV)
{
    const int w = threadIdx.x >> 6, l = threadIdx.x & 63;
    const int n = blockIdx.x * 4 + w;             // 4096 windows
    u16* base = QKV + (size_t)n * 4 * 3072;
    const float scale = 0.03125f;                 // C^-0.5 = 1/32 (d_model!)
#pragma unroll
    for (int c = 0; c < 2; ++c) {
        const int col = c * 512 + l * 8;
        u16x8 qr[4], kr[4], vr[4];
#pragma unroll
        for (int t = 0; t < 4; ++t) {
            qr[t] = *(const u16x8*)(base + t * 3072 + col);
            kr[t] = *(const u16x8*)(base + t * 3072 + 1024 + col);
            vr[t] = *(const u16x8*)(base + t * 3072 + 2048 + col);
        }
        float qf[4][8], kf[4][8];
#pragma unroll
        for (int t = 0; t < 4; ++t)
#pragma unroll
            for (int j = 0; j < 8; ++j) { qf[t][j] = b2f(qr[t][j]); kf[t][j] = b2f(kr[t][j]); }
        float s[4][4];
#pragma unroll
        for (int t = 0; t < 4; ++t)
#pragma unroll
            for (int u = 0; u < 4; ++u) {
                float p = qf[t][0] * kf[u][0];
#pragma unroll
                for (int j = 1; j < 8; ++j) p += qf[t][j] * kf[u][j];
                p += __shfl_xor(p, 1); p += __shfl_xor(p, 2); p += __shfl_xor(p, 4);
                s[t][u] = p * scale;              // per-head dot (8-lane group)
            }
#pragma unroll
        for (int t = 0; t < 4; ++t) {
            const float m = fmaxf(fmaxf(s[t][0], s[t][1]), fmaxf(s[t][2], s[t][3]));
            const float e0 = expf(s[t][0] - m), e1 = expf(s[t][1] - m);
            const float e2 = expf(s[t][2] - m), e3 = expf(s[t][3] - m);
            const float inv = 1.f / (e0 + e1 + e2 + e3);
            u16x8 o;
#pragma unroll
            for (int j = 0; j < 8; ++j)
                o[j] = f2b((e0 * b2f(vr[0][j]) + e1 * b2f(vr[1][j]) +
                            e2 * b2f(vr[2][j]) + e3 * b2f(vr[3][j])) * inv);
            *(u16x8*)(base + t * 3072 + col) = o; // overwrite own q slot (wave-private)
        }
    }
}

// ---------- launch ----------
extern "C" void kernel_launch(void* const* d_in, const int* in_sizes, int n_in,
                              void* d_out, int out_size, void* d_ws, size_t ws_size,
                              hipStream_t stream)
{
    const float* x    = (const float*)d_in[0];
    const float* ln1g = (const float*)d_in[1];
    const float* ln1b = (const float*)d_in[2];
    const float* Wq   = (const float*)d_in[3];
    const float* Wk   = (const float*)d_in[4];
    const float* Wv   = (const float*)d_in[5];
    const float* Wp   = (const float*)d_in[6];
    const float* bp   = (const float*)d_in[7];
    const float* ln2g = (const float*)d_in[8];
    const float* ln2b = (const float*)d_in[9];
    const float* W1   = (const float*)d_in[10];
    const float* b1   = (const float*)d_in[11];
    const float* W2   = (const float*)d_in[12];
    const float* b2   = (const float*)d_in[13];
    float* out = (float*)d_out;

    char* ws = (char*)d_ws;
    const size_t MB = 1024 * 1024;
    u16* xr_b  = (u16*)ws;                        // 32MB: xr bf16 (residual spine)
    u16* xw_b  = (u16*)(ws + 32 * MB);            // 32MB: ln1(x) windowed bf16
    u16* qkv   = (u16*)(ws + 64 * MB);            // 96MB: q|k|v; attn in-place; dead after proj
    u16* h1b   = (u16*)(ws + 64 * MB);            // 32MB: reuse of qkv region after proj
    u16* ln2bf = (u16*)(ws + 160 * MB);           // 32MB
    u16* WqkvT = (u16*)(ws + 192 * MB);           // 6MB [3072][1024]
    u16* WpT   = (u16*)(ws + 198 * MB);           // 3 x 2MB contiguous
    u16* W1T   = WpT + (1u << 20);
    u16* W2T   = W1T + (1u << 20);

    hipFuncSetAttribute((const void*)gemm256<0>, hipFuncAttributeMaxDynamicSharedMemorySize, 131072);
    hipFuncSetAttribute((const void*)gemm256<2>, hipFuncAttributeMaxDynamicSharedMemorySize, 131072);
    hipFuncSetAttribute((const void*)gemm256<3>, hipFuncAttributeMaxDynamicSharedMemorySize, 131072);
    hipFuncSetAttribute((const void*)gemm256<5>, hipFuncAttributeMaxDynamicSharedMemorySize, 131072);

    const int M = 16384, K = 1024;
    dim3 tpb(32, 8);
    transpose_qkv<<<dim3(2, 32, 48), tpb, 0, stream>>>(Wq, Wk, Wv, WqkvT);
    transpose_pw <<<dim3(32, 32, 3), tpb, 0, stream>>>(Wp, W1, W2, WpT);

    ln_kernel<1, 0><<<16384, 256, 0, stream>>>(x, ln1g, ln1b, xw_b);

    // qkv = xw @ [Wq|Wk|Wv]   (N=3072)
    gemm256<0><<<768, 512, 131072, stream>>>(xw_b, WqkvT, nullptr, nullptr, qkv, M, 3072, K, K, 12);

    attn_kernel<<<1024, 256, 0, stream>>>(qkv);    // att overwrites q columns

    // xr = att @ Wp + bp + xw  -> bf16 spine
    gemm256<5><<<256, 512, 131072, stream>>>(qkv, WpT, bp, xw_b, xr_b, M, 1024, K, 3072, 4);

    ln_kernel<0, 1><<<16384, 256, 0, stream>>>(xr_b, ln2g, ln2b, ln2bf);

    // h1 = gelu(ln2 @ W1 + b1)   (qkv region is dead now -> h1b)
    gemm256<2><<<256, 512, 131072, stream>>>(ln2bf, W1T, b1, nullptr, h1b, M, 1024, K, K, 4);

    // out[natrow] = h1 @ W2 + b2 + xr
    gemm256<3><<<256, 512, 131072, stream>>>(h1b, W2T, b2, xr_b, out, M, 1024, K, K, 4);
}